// Round 1
// baseline (983.349 us; speedup 1.0000x reference)
//
#include <hip/hip_runtime.h>
#include <stdint.h>

#define HW 9216   // 96*96

typedef float f32x4 __attribute__((ext_vector_type(4)));
typedef short s16x8 __attribute__((ext_vector_type(8)));

__device__ __forceinline__ unsigned short f2bf(float f){
  union { float fv; uint32_t u; } x; x.fv = f;
  uint32_t u = x.u;
  u += 0x7fffu + ((u >> 16) & 1u);   // RNE
  return (unsigned short)(u >> 16);
}
__device__ __forceinline__ float bf2f(unsigned short s){
  union { uint32_t u; float fv; } x; x.u = ((uint32_t)s) << 16;
  return x.fv;
}

// ---------------- weight pack: Wp[o][kl], kl = chunk*288 + tap*32 + ci ----------------
__global__ void packw_kernel(const float* __restrict__ w, unsigned short* __restrict__ Wp, int Cin){
  int K = Cin * 9;
  int total = 64 * K;
  for (int i = blockIdx.x * blockDim.x + threadIdx.x; i < total; i += gridDim.x * blockDim.x){
    int o = i / K; int kl = i - o * K;
    int ch = kl / 288; int wi = kl - ch * 288; int tap = wi >> 5; int ci = wi & 31;
    int cin = ch * 32 + ci;
    Wp[i] = f2bf(w[((size_t)o * Cin + cin) * 9 + tap]);
  }
}

// ---------------- conv3x3 implicit GEMM, tile 8h x 16w (M=128) x N=64, bf16 MFMA ----------------
// grid.x = 144 m-tiles (2b * 12h * 6w), grid.y = K-split; accumulate via atomicAdd into f32 buffer.
__global__ __launch_bounds__(256) void conv3x3_kernel(
    const float* __restrict__ src0, const float* __restrict__ src1, int C0,
    const unsigned short* __restrict__ Wp, int Ktot,
    float* __restrict__ accum, int nchunks){
  int mt = blockIdx.x;
  int b = mt / 72; int r = mt - b * 72;
  int h0 = (r / 6) * 8, w0 = (r % 6) * 16;
  int KS = gridDim.y, ks = blockIdx.y;
  int c0 = (nchunks * ks) / KS, c1 = (nchunks * (ks + 1)) / KS;
  int tid = threadIdx.x, lane = tid & 63, wave = tid >> 6;
  int wm = wave >> 1, wn = wave & 1;
  int ln = lane & 15, kg = lane >> 4;
  __shared__ unsigned short halo[2][7200];   // [10h][18w][40c-pad] bf16, double-buffered
  f32x4 acc[4][2];
  #pragma unroll
  for (int i = 0; i < 4; i++){ acc[i][0] = (f32x4)(0.f); acc[i][1] = (f32x4)(0.f); }

  auto stage = [&](int buf, int ck){
    int cbase = ck * 32;
    const float* s;
    if (cbase < C0) s = src0 + ((size_t)b * C0 + cbase) * HW;
    else            s = src1 + ((size_t)b * 64 + (cbase - C0)) * HW;   // concat tail = 64ch
    #pragma unroll 1
    for (int e = tid; e < 5760; e += 256){
      int c = e / 180; int rm = e - c * 180; int hh = rm / 18; int ww = rm - hh * 18;
      int h = h0 - 1 + hh, w = w0 - 1 + ww;
      float v = 0.f;
      if ((unsigned)h < 96u && (unsigned)w < 96u) v = s[(size_t)c * HW + h * 96 + w];
      halo[buf][(hh * 18 + ww) * 40 + c] = f2bf(v);
    }
  };
  stage(0, c0);
  __syncthreads();
  for (int ck = c0; ck < c1; ck++){
    int cur = (ck - c0) & 1;
    if (ck + 1 < c1) stage(cur ^ 1, ck + 1);
    const unsigned short* wrow = Wp + (size_t)ck * 288;
    #pragma unroll 1
    for (int tap = 0; tap < 9; tap++){
      int dy = tap / 3, dx = tap - dy * 3;
      s16x8 bfr0 = *(const s16x8*)(wrow + (size_t)(wn * 32 + ln) * Ktot + tap * 32 + kg * 8);
      s16x8 bfr1 = *(const s16x8*)(wrow + (size_t)(wn * 32 + 16 + ln) * Ktot + tap * 32 + kg * 8);
      #pragma unroll
      for (int mf = 0; mf < 4; mf++){
        int hh = wm * 4 + mf + dy;
        int ww = ln + dx;
        s16x8 af = *(const s16x8*)(&halo[cur][(hh * 18 + ww) * 40 + kg * 8]);
        acc[mf][0] = __builtin_amdgcn_mfma_f32_16x16x32_bf16(af, bfr0, acc[mf][0], 0, 0, 0);
        acc[mf][1] = __builtin_amdgcn_mfma_f32_16x16x32_bf16(af, bfr1, acc[mf][1], 0, 0, 0);
      }
    }
    __syncthreads();
  }
  #pragma unroll
  for (int mf = 0; mf < 4; mf++){
    #pragma unroll
    for (int nf = 0; nf < 2; nf++){
      int o = wn * 32 + nf * 16 + ln;
      #pragma unroll
      for (int rr = 0; rr < 4; rr++){
        int m = wm * 64 + mf * 16 + kg * 4 + rr;
        int h = h0 + (m >> 4), w = w0 + (m & 15);
        atomicAdd(&accum[((size_t)b * 64 + o) * HW + h * 96 + w], acc[mf][nf][rr]);
      }
    }
  }
}

// ---------------- BN (+optional ReLU) epilogue ----------------
__global__ void bn_act_kernel(const float* __restrict__ a, float* __restrict__ o,
    const float* __restrict__ g, const float* __restrict__ bb,
    const float* __restrict__ m, const float* __restrict__ v, int relu){
  int i = blockIdx.x * 256 + threadIdx.x;
  int c = (i / HW) & 63;
  float sc = g[c] * rsqrtf(v[c] + 1e-5f);
  float val = (a[i] - m[c]) * sc + bb[c];
  if (relu) val = fmaxf(val, 0.f);
  o[i] = val;
}

// ---------------- CCA: q,k,v projections (1x1) ----------------
__global__ __launch_bounds__(128) void cca_proj_kernel(const float* __restrict__ xin,
    const float* __restrict__ wq, const float* __restrict__ wk, const float* __restrict__ wv,
    float* __restrict__ q, float* __restrict__ k, float* __restrict__ v){
  __shared__ float wqL[512], wkL[512], wvL[4096];
  int tid = threadIdx.x;
  for (int i = tid; i < 512; i += 128){ wqL[i] = wq[i]; wkL[i] = wk[i]; }
  for (int i = tid; i < 4096; i += 128) wvL[i] = wv[i];
  __syncthreads();
  int gp = blockIdx.x * 128 + tid;
  int b = gp / HW, pos = gp - b * HW;
  float qa[8], ka[8], va[64];
  #pragma unroll
  for (int d = 0; d < 8; d++){ qa[d] = 0.f; ka[d] = 0.f; }
  #pragma unroll
  for (int d = 0; d < 64; d++) va[d] = 0.f;
  const float* xb = xin + (size_t)b * 64 * HW + pos;
  #pragma unroll 4
  for (int c = 0; c < 64; c++){
    float xv = xb[(size_t)c * HW];
    #pragma unroll
    for (int d = 0; d < 8; d++){ qa[d] += wqL[d * 64 + c] * xv; ka[d] += wkL[d * 64 + c] * xv; }
    #pragma unroll
    for (int d = 0; d < 64; d++) va[d] += wvL[d * 64 + c] * xv;
  }
  #pragma unroll
  for (int d = 0; d < 8; d++){
    q[((size_t)b * 8 + d) * HW + pos] = qa[d];
    k[((size_t)b * 8 + d) * HW + pos] = ka[d];
  }
  #pragma unroll
  for (int d = 0; d < 64; d++) v[((size_t)b * 64 + d) * HW + pos] = va[d];
}

// ---------------- CCA: column energies eH (with diagonal mask) ----------------
// block = (b, w). ebuf layout: [b][w][h][kp], kp indexes H.
__global__ __launch_bounds__(256) void cca_colE_kernel(const float* __restrict__ q,
    const float* __restrict__ k, float* __restrict__ ebuf){
  int blk = blockIdx.x; int b = blk / 96, w = blk - b * 96;
  __shared__ float qc[768], kc[768];
  int tid = threadIdx.x;
  for (int i = tid; i < 768; i += 256){
    int d = i / 96, hp = i - d * 96;
    qc[i] = q[((size_t)b * 8 + d) * HW + hp * 96 + w];
    kc[i] = k[((size_t)b * 8 + d) * HW + hp * 96 + w];
  }
  __syncthreads();
  float* eb = ebuf + ((size_t)b * 96 + w) * HW;
  for (int i = tid; i < 9216; i += 256){
    int h = i / 96, kp = i - h * 96;
    float e = 0.f;
    #pragma unroll
    for (int d = 0; d < 8; d++) e += qc[d * 96 + h] * kc[d * 96 + kp];
    eb[i] = (kp == h) ? -1e30f : e;
  }
}

// ---------------- CCA: row kernel — eW, joint softmax over [eH|eW], oW, partial output ----------------
// block = (b, h). Normalized eH written back in-place to ebuf; out = xin + gamma*oW.
__global__ __launch_bounds__(256) void cca_rowSM_kernel(const float* __restrict__ q,
    const float* __restrict__ k, const float* __restrict__ v, const float* __restrict__ xin,
    const float* __restrict__ gamma, float* __restrict__ ebuf, float* __restrict__ xout){
  int blk = blockIdx.x; int b = blk / 96, h = blk - b * 96;
  __shared__ float qr[768], kr[768];
  __shared__ unsigned short vr[6144];      // [64][96] bf16
  __shared__ float ew[9312];               // [96][97]
  int tid = threadIdx.x;
  for (int i = tid; i < 768; i += 256){
    int d = i / 96, wp = i - d * 96;
    qr[i] = q[((size_t)b * 8 + d) * HW + h * 96 + wp];
    kr[i] = k[((size_t)b * 8 + d) * HW + h * 96 + wp];
  }
  for (int i = tid; i < 6144; i += 256){
    int d = i / 96, wp = i - d * 96;
    vr[i] = f2bf(v[((size_t)b * 64 + d) * HW + h * 96 + wp]);
  }
  __syncthreads();
  for (int i = tid; i < 9216; i += 256){
    int w = i / 96, kp = i - w * 96;
    float e = 0.f;
    #pragma unroll
    for (int d = 0; d < 8; d++) e += qr[d * 96 + w] * kr[d * 96 + kp];
    ew[w * 97 + kp] = e;
  }
  __syncthreads();
  int lane = tid & 63, wvid = tid >> 6;
  for (int w = wvid; w < 96; w += 4){
    float* eb = ebuf + (((size_t)b * 96 + w) * 96 + h) * 96;
    float x0 = eb[lane];                                            // j = lane      (eH 0..63)
    float x1 = (lane < 32) ? eb[64 + lane] : ew[w * 97 + (lane - 32)]; // j = lane+64
    float x2 = ew[w * 97 + (lane + 32)];                            // j = lane+128  (eW 32..95)
    float mx = fmaxf(x0, fmaxf(x1, x2));
    #pragma unroll
    for (int s = 32; s; s >>= 1) mx = fmaxf(mx, __shfl_xor(mx, s));
    float e0 = __expf(x0 - mx), e1 = __expf(x1 - mx), e2 = __expf(x2 - mx);
    float sm = e0 + e1 + e2;
    #pragma unroll
    for (int s = 32; s; s >>= 1) sm += __shfl_xor(sm, s);
    float inv = 1.f / sm;
    eb[lane] = e0 * inv;
    if (lane < 32) eb[64 + lane] = e1 * inv; else ew[w * 97 + (lane - 32)] = e1 * inv;
    ew[w * 97 + (lane + 32)] = e2 * inv;
  }
  __syncthreads();
  float gm = gamma[0];
  for (int i = tid; i < 6144; i += 256){
    int d = i / 96, w = i - d * 96;
    float o = 0.f;
    #pragma unroll 4
    for (int kp = 0; kp < 96; kp++) o += ew[w * 97 + kp] * bf2f(vr[d * 96 + kp]);
    size_t idx = ((size_t)b * 64 + d) * HW + h * 96 + w;
    xout[idx] = xin[idx] + gm * o;
  }
}

// ---------------- CCA: column kernel — oH, final accumulate ----------------
__global__ __launch_bounds__(256) void cca_colO_kernel(const float* __restrict__ v,
    const float* __restrict__ gamma, const float* __restrict__ ebuf, float* __restrict__ xout){
  int blk = blockIdx.x; int b = blk / 96, w = blk - b * 96;
  __shared__ float vc[6144];   // [64][96]
  __shared__ float aH[9312];   // [96][97]
  int tid = threadIdx.x;
  for (int i = tid; i < 6144; i += 256){
    int d = i / 96, hp = i - d * 96;
    vc[i] = v[((size_t)b * 64 + d) * HW + hp * 96 + w];
  }
  const float* eb = ebuf + ((size_t)b * 96 + w) * HW;
  for (int i = tid; i < 9216; i += 256){
    int hh = i / 96, kp = i - hh * 96;
    aH[hh * 97 + kp] = eb[i];
  }
  __syncthreads();
  float gm = gamma[0];
  for (int i = tid; i < 6144; i += 256){
    int d = i / 96, hh = i - d * 96;
    float o = 0.f;
    #pragma unroll 4
    for (int kp = 0; kp < 96; kp++) o += aH[hh * 97 + kp] * vc[d * 96 + kp];
    size_t idx = ((size_t)b * 64 + d) * HW + hh * 96 + w;
    xout[idx] += gm * o;
  }
}

// ---------------- cls2 1x1 conv 64->19 at low res (commutes with upsample) ----------------
__global__ __launch_bounds__(256) void cls2_kernel(const float* __restrict__ y,
    const float* __restrict__ w2, float* __restrict__ t19){
  __shared__ float w2L[19 * 64];
  int tid = threadIdx.x;
  for (int i = tid; i < 19 * 64; i += 256) w2L[i] = w2[i];
  __syncthreads();
  int gp = blockIdx.x * 256 + tid;
  int b = gp / HW, pos = gp - b * HW;
  float acc[19];
  #pragma unroll
  for (int o = 0; o < 19; o++) acc[o] = 0.f;
  const float* yb = y + (size_t)b * 64 * HW + pos;
  #pragma unroll 4
  for (int c = 0; c < 64; c++){
    float xv = yb[(size_t)c * HW];
    #pragma unroll
    for (int o = 0; o < 19; o++) acc[o] += w2L[o * 64 + c] * xv;
  }
  #pragma unroll
  for (int o = 0; o < 19; o++) t19[((size_t)b * 19 + o) * HW + pos] = acc[o];
}

// ---------------- bilinear x8 upsample (align_corners) of 19ch ----------------
__global__ void upsample_kernel(const float* __restrict__ t19, float* __restrict__ out){
  int gid = blockIdx.x * 256 + threadIdx.x;   // 2*19*768*192 threads, 4 x-outputs each
  int xq = gid % 192; int t = gid / 192;
  int yy = t % 768; t /= 768;
  int o = t % 19; int b = t / 19;
  const float R = 95.0f / 767.0f;
  float ry = yy * R;
  int iy = (int)ry;
  float fy = ry - (float)iy;
  int iy1 = min(iy + 1, 95);
  const float* base = t19 + ((size_t)b * 19 + o) * HW;
  float4 res;
  float* rp = (float*)&res;
  #pragma unroll
  for (int j = 0; j < 4; j++){
    int xx = xq * 4 + j;
    float rx = xx * R;
    int ix = (int)rx; float fx = rx - (float)ix; int ix1 = min(ix + 1, 95);
    float v00 = base[iy * 96 + ix],  v01 = base[iy * 96 + ix1];
    float v10 = base[iy1 * 96 + ix], v11 = base[iy1 * 96 + ix1];
    rp[j] = (1.f - fy) * ((1.f - fx) * v00 + fx * v01) + fy * ((1.f - fx) * v10 + fx * v11);
  }
  *(float4*)(out + (((size_t)b * 19 + o) * 768 + yy) * 768 + xq * 4) = res;
}

// ---------------- host-side orchestration ----------------
extern "C" void kernel_launch(void* const* d_in, const int* in_sizes, int n_in,
                              void* d_out, int out_size, void* d_ws, size_t ws_size,
                              hipStream_t stream){
  const float* x       = (const float*)d_in[0];
  const float* w_in    = (const float*)d_in[1];
  const float* bn_in_g = (const float*)d_in[2];
  const float* bn_in_b = (const float*)d_in[3];
  const float* bn_in_m = (const float*)d_in[4];
  const float* bn_in_v = (const float*)d_in[5];
  const float* wq      = (const float*)d_in[6];
  const float* wk      = (const float*)d_in[7];
  const float* wv      = (const float*)d_in[8];
  const float* gamma   = (const float*)d_in[9];
  const float* w_out   = (const float*)d_in[10];
  const float* bn_o_g  = (const float*)d_in[11];
  const float* bn_o_b  = (const float*)d_in[12];
  const float* bn_o_m  = (const float*)d_in[13];
  const float* bn_o_v  = (const float*)d_in[14];
  const float* w_cls1  = (const float*)d_in[15];
  const float* bn_c_g  = (const float*)d_in[16];
  const float* bn_c_b  = (const float*)d_in[17];
  const float* bn_c_m  = (const float*)d_in[18];
  const float* bn_c_v  = (const float*)d_in[19];
  const float* w_cls2  = (const float*)d_in[20];
  float* out = (float*)d_out;

  char* ws = (char*)d_ws;
  size_t off = 0;
  auto alloc = [&](size_t bytes) -> void* {
    void* p = ws + off; off += (bytes + 255) & ~(size_t)255; return p;
  };
  const size_t NCHWf = (size_t)2 * 64 * HW * 4;          // 4.72 MB
  float* accum = (float*)alloc(NCHWf);
  float* xattA = (float*)alloc(NCHWf);
  float* xattB = (float*)alloc(NCHWf);
  float* mid   = (float*)alloc(NCHWf);
  float* ybuf  = (float*)alloc(NCHWf);
  float* qb    = (float*)alloc((size_t)2 * 8 * HW * 4);
  float* kb    = (float*)alloc((size_t)2 * 8 * HW * 4);
  float* vb    = (float*)alloc(NCHWf);
  float* ebuf  = (float*)alloc((size_t)2 * 96 * HW * 4); // 7.08 MB
  float* t19   = (float*)alloc((size_t)2 * 19 * HW * 4);
  unsigned short* WpIn  = (unsigned short*)alloc((size_t)64 * 2048 * 9 * 2);
  unsigned short* WpOut = (unsigned short*)alloc((size_t)64 * 64 * 9 * 2);
  unsigned short* WpCls = (unsigned short*)alloc((size_t)64 * 2112 * 9 * 2);
  (void)ws_size; (void)in_sizes; (void)n_in; (void)out_size;

  // weight packs (bf16, MFMA-friendly [o][k] layout)
  packw_kernel<<<1024, 256, 0, stream>>>(w_in,   WpIn,  2048);
  packw_kernel<<<64,   256, 0, stream>>>(w_out,  WpOut, 64);
  packw_kernel<<<1024, 256, 0, stream>>>(w_cls1, WpCls, 2112);

  // conv_in (2048 -> 64) + BN + ReLU
  hipMemsetAsync(accum, 0, NCHWf, stream);
  conv3x3_kernel<<<dim3(144, 4), 256, 0, stream>>>(x, nullptr, 2048, WpIn, 2048 * 9, accum, 64);
  bn_act_kernel<<<4608, 256, 0, stream>>>(accum, xattA, bn_in_g, bn_in_b, bn_in_m, bn_in_v, 1);

  // CCA pass 1: xattA -> xattB
  cca_proj_kernel<<<144, 128, 0, stream>>>(xattA, wq, wk, wv, qb, kb, vb);
  cca_colE_kernel<<<192, 256, 0, stream>>>(qb, kb, ebuf);
  cca_rowSM_kernel<<<192, 256, 0, stream>>>(qb, kb, vb, xattA, gamma, ebuf, xattB);
  cca_colO_kernel<<<192, 256, 0, stream>>>(vb, gamma, ebuf, xattB);
  // CCA pass 2: xattB -> xattA
  cca_proj_kernel<<<144, 128, 0, stream>>>(xattB, wq, wk, wv, qb, kb, vb);
  cca_colE_kernel<<<192, 256, 0, stream>>>(qb, kb, ebuf);
  cca_rowSM_kernel<<<192, 256, 0, stream>>>(qb, kb, vb, xattB, gamma, ebuf, xattA);
  cca_colO_kernel<<<192, 256, 0, stream>>>(vb, gamma, ebuf, xattA);

  // conv_out (64 -> 64) + BN + ReLU
  hipMemsetAsync(accum, 0, NCHWf, stream);
  conv3x3_kernel<<<dim3(144, 1), 256, 0, stream>>>(xattA, nullptr, 64, WpOut, 64 * 9, accum, 2);
  bn_act_kernel<<<4608, 256, 0, stream>>>(accum, mid, bn_o_g, bn_o_b, bn_o_m, bn_o_v, 1);

  // cls1 conv on concat([x, mid]) (2112 -> 64) + BN (no relu)
  hipMemsetAsync(accum, 0, NCHWf, stream);
  conv3x3_kernel<<<dim3(144, 4), 256, 0, stream>>>(x, mid, 2048, WpCls, 2112 * 9, accum, 66);
  bn_act_kernel<<<4608, 256, 0, stream>>>(accum, ybuf, bn_c_g, bn_c_b, bn_c_m, bn_c_v, 0);

  // cls2 (1x1, 64->19) at 96x96, then bilinear x8 upsample (commuted with 1x1 conv)
  cls2_kernel<<<72, 256, 0, stream>>>(ybuf, w_cls2, t19);
  upsample_kernel<<<21888, 256, 0, stream>>>(t19, out);
}

// Round 2
// 849.843 us; speedup vs baseline: 1.1571x; 1.1571x over previous
//
#include <hip/hip_runtime.h>
#include <stdint.h>

#define HW 9216   // 96*96

typedef float f32x4 __attribute__((ext_vector_type(4)));
typedef short s16x8 __attribute__((ext_vector_type(8)));

__device__ __forceinline__ unsigned short f2bf(float f){
  union { float fv; uint32_t u; } x; x.fv = f;
  uint32_t u = x.u;
  u += 0x7fffu + ((u >> 16) & 1u);   // RNE
  return (unsigned short)(u >> 16);
}
__device__ __forceinline__ float bf2f(unsigned short s){
  union { uint32_t u; float fv; } x; x.u = ((uint32_t)s) << 16;
  return x.fv;
}

// ---------------- weight pack: Wp[((ck*9 + tap)*64 + o)*32 + c] ----------------
// B-fragment loads become contiguous 1KB per wave (o-major, c-innermost).
__global__ void packw_kernel(const float* __restrict__ w, unsigned short* __restrict__ Wp, int Cin){
  int total = 64 * Cin * 9;
  for (int i = blockIdx.x * blockDim.x + threadIdx.x; i < total; i += gridDim.x * blockDim.x){
    int c = i & 31; int r = i >> 5; int o = r & 63; int r2 = r >> 6;
    int tap = r2 % 9; int ck = r2 / 9;
    Wp[i] = f2bf(w[((size_t)o * Cin + ck * 32 + c) * 9 + tap]);
  }
}

// ---------------- conv3x3 implicit GEMM, tile 8h x 16w (M=128) x N=64, bf16 MFMA ----------------
// Reg-staged halo (T14 split: loads before tap loop, cvt+ds_write after), XOR-swizzled LDS,
// f32 NCHW input read directly (transpose-in-registers), atomicAdd f32 K-split epilogue.
__global__ __launch_bounds__(256) void conv3x3_kernel(
    const float* __restrict__ S0, const float* __restrict__ S1, int nck0,
    const unsigned short* __restrict__ Wp,
    float* __restrict__ accum, int nchunks){
  int mt = blockIdx.x;
  int b = mt / 72; int r = mt - b * 72;
  int h0 = (r / 6) * 8, w0 = (r % 6) * 16;
  int KS = gridDim.y, ks = blockIdx.y;
  int c0 = (nchunks * ks) / KS, c1 = (nchunks * (ks + 1)) / KS;
  int tid = threadIdx.x, lane = tid & 63, wv = tid >> 6;
  int wm = wv >> 1, wn = wv & 1;
  int ln = lane & 15, kg = lane >> 4;
  __shared__ unsigned short halo[2][5760];   // 2 x 180pix x 32c (16B-quad XOR-swizzled)

  // staging item decode: item i = kq*180 + pix  (kq-major -> coalesced global reads)
  int goffE[3]; int lws[3]; bool val[3]; bool exist[3];
  #pragma unroll
  for (int it = 0; it < 3; it++){
    int i = tid + it * 256;
    int kq = i / 180, pix = i - kq * 180;
    int hh = pix / 18, ww = pix - hh * 18;
    int h = h0 - 1 + hh, w = w0 - 1 + ww;
    exist[it] = (i < 720);
    bool v = exist[it] && ((unsigned)h < 96u) && ((unsigned)w < 96u);
    val[it] = v;
    goffE[it] = v ? (kq * 8 * HW + h * 96 + w) : 0;
    lws[it] = pix * 32 + (((kq ^ ((pix >> 1) & 3)) & 3) << 3);
  }

  float rbuf[3][8];
  auto ldstage = [&](int ck){
    const float* base = (ck < nck0)
      ? S0 + ((size_t)b * nck0 + ck) * (size_t)(32 * HW)
      : S1 + ((size_t)b * 2 + (ck - nck0)) * (size_t)(32 * HW);
    #pragma unroll
    for (int it = 0; it < 3; it++){
      if (val[it]){
        #pragma unroll
        for (int j = 0; j < 8; j++) rbuf[it][j] = base[goffE[it] + j * HW];
      }
    }
  };
  auto wstage = [&](int buf){
    #pragma unroll
    for (int it = 0; it < 3; it++){
      if (exist[it]){
        s16x8 pk;
        #pragma unroll
        for (int j = 0; j < 8; j++) pk[j] = val[it] ? (short)f2bf(rbuf[it][j]) : (short)0;
        *(s16x8*)(&halo[buf][lws[it]]) = pk;
      }
    }
  };

  f32x4 acc[4][2];
  #pragma unroll
  for (int i = 0; i < 4; i++){ acc[i][0] = (f32x4)(0.f); acc[i][1] = (f32x4)(0.f); }

  ldstage(c0);
  wstage(0);
  __syncthreads();

  for (int ck = c0; ck < c1; ck++){
    int cur = (ck - c0) & 1;
    bool pf = (ck + 1 < c1);
    if (pf) ldstage(ck + 1);                    // issue-early: HBM latency hides under MFMAs
    const unsigned short* wb = Wp + (size_t)ck * 18432 + (wn * 32 + ln) * 32 + kg * 8;
    #pragma unroll
    for (int tap = 0; tap < 9; tap++){
      int dy = tap / 3, dx = tap - dy * 3;
      s16x8 b0 = *(const s16x8*)(wb + tap * 2048);
      s16x8 b1 = *(const s16x8*)(wb + tap * 2048 + 512);   // +16 o's
      #pragma unroll
      for (int mf = 0; mf < 4; mf++){
        int pix = (wm * 4 + mf + dy) * 18 + ln + dx;
        int aoff = pix * 32 + (((kg ^ ((pix >> 1) & 3)) & 3) << 3);
        s16x8 a = *(const s16x8*)(&halo[cur][aoff]);
        acc[mf][0] = __builtin_amdgcn_mfma_f32_16x16x32_bf16(a, b0, acc[mf][0], 0, 0, 0);
        acc[mf][1] = __builtin_amdgcn_mfma_f32_16x16x32_bf16(a, b1, acc[mf][1], 0, 0, 0);
      }
    }
    if (pf) wstage(cur ^ 1);                    // write-late: after MFMAs, before barrier
    __syncthreads();
  }

  #pragma unroll
  for (int mf = 0; mf < 4; mf++){
    #pragma unroll
    for (int nf = 0; nf < 2; nf++){
      int o = wn * 32 + nf * 16 + ln;
      #pragma unroll
      for (int rr = 0; rr < 4; rr++){
        int m = wm * 64 + mf * 16 + kg * 4 + rr;
        int h = h0 + (m >> 4), w = w0 + (m & 15);
        atomicAdd(&accum[((size_t)b * 64 + o) * HW + h * 96 + w], acc[mf][nf][rr]);
      }
    }
  }
}

// ---------------- BN (+optional ReLU) epilogue ----------------
__global__ void bn_act_kernel(const float* __restrict__ a, float* __restrict__ o,
    const float* __restrict__ g, const float* __restrict__ bb,
    const float* __restrict__ m, const float* __restrict__ v, int relu){
  int i = blockIdx.x * 256 + threadIdx.x;
  int c = (i / HW) & 63;
  float sc = g[c] * rsqrtf(v[c] + 1e-5f);
  float val = (a[i] - m[c]) * sc + bb[c];
  if (relu) val = fmaxf(val, 0.f);
  o[i] = val;
}

// ---------------- CCA: q,k,v projections (1x1) ----------------
__global__ __launch_bounds__(128) void cca_proj_kernel(const float* __restrict__ xin,
    const float* __restrict__ wq, const float* __restrict__ wk, const float* __restrict__ wv,
    float* __restrict__ q, float* __restrict__ k, float* __restrict__ v){
  __shared__ float wqL[512], wkL[512], wvL[4096];
  int tid = threadIdx.x;
  for (int i = tid; i < 512; i += 128){ wqL[i] = wq[i]; wkL[i] = wk[i]; }
  for (int i = tid; i < 4096; i += 128) wvL[i] = wv[i];
  __syncthreads();
  int gp = blockIdx.x * 128 + tid;
  int b = gp / HW, pos = gp - b * HW;
  float qa[8], ka[8], va[64];
  #pragma unroll
  for (int d = 0; d < 8; d++){ qa[d] = 0.f; ka[d] = 0.f; }
  #pragma unroll
  for (int d = 0; d < 64; d++) va[d] = 0.f;
  const float* xb = xin + (size_t)b * 64 * HW + pos;
  #pragma unroll 4
  for (int c = 0; c < 64; c++){
    float xv = xb[(size_t)c * HW];
    #pragma unroll
    for (int d = 0; d < 8; d++){ qa[d] += wqL[d * 64 + c] * xv; ka[d] += wkL[d * 64 + c] * xv; }
    #pragma unroll
    for (int d = 0; d < 64; d++) va[d] += wvL[d * 64 + c] * xv;
  }
  #pragma unroll
  for (int d = 0; d < 8; d++){
    q[((size_t)b * 8 + d) * HW + pos] = qa[d];
    k[((size_t)b * 8 + d) * HW + pos] = ka[d];
  }
  #pragma unroll
  for (int d = 0; d < 64; d++) v[((size_t)b * 64 + d) * HW + pos] = va[d];
}

// ---------------- CCA: column energies eH (with diagonal mask) ----------------
__global__ __launch_bounds__(256) void cca_colE_kernel(const float* __restrict__ q,
    const float* __restrict__ k, float* __restrict__ ebuf){
  int blk = blockIdx.x; int b = blk / 96, w = blk - b * 96;
  __shared__ float qc[768], kc[768];
  int tid = threadIdx.x;
  for (int i = tid; i < 768; i += 256){
    int d = i / 96, hp = i - d * 96;
    qc[i] = q[((size_t)b * 8 + d) * HW + hp * 96 + w];
    kc[i] = k[((size_t)b * 8 + d) * HW + hp * 96 + w];
  }
  __syncthreads();
  float* eb = ebuf + ((size_t)b * 96 + w) * HW;
  for (int i = tid; i < 9216; i += 256){
    int h = i / 96, kp = i - h * 96;
    float e = 0.f;
    #pragma unroll
    for (int d = 0; d < 8; d++) e += qc[d * 96 + h] * kc[d * 96 + kp];
    eb[i] = (kp == h) ? -1e30f : e;
  }
}

// ---------------- CCA: row kernel — eW, joint softmax over [eH|eW], oW, partial output ----------------
__global__ __launch_bounds__(256) void cca_rowSM_kernel(const float* __restrict__ q,
    const float* __restrict__ k, const float* __restrict__ v, const float* __restrict__ xin,
    const float* __restrict__ gamma, float* __restrict__ ebuf, float* __restrict__ xout){
  int blk = blockIdx.x; int b = blk / 96, h = blk - b * 96;
  __shared__ float qr[768], kr[768];
  __shared__ unsigned short vr[6144];      // [64][96] bf16
  __shared__ float ew[9312];               // [96][97]
  int tid = threadIdx.x;
  for (int i = tid; i < 768; i += 256){
    int d = i / 96, wp = i - d * 96;
    qr[i] = q[((size_t)b * 8 + d) * HW + h * 96 + wp];
    kr[i] = k[((size_t)b * 8 + d) * HW + h * 96 + wp];
  }
  for (int i = tid; i < 6144; i += 256){
    int d = i / 96, wp = i - d * 96;
    vr[i] = f2bf(v[((size_t)b * 64 + d) * HW + h * 96 + wp]);
  }
  __syncthreads();
  for (int i = tid; i < 9216; i += 256){
    int w = i / 96, kp = i - w * 96;
    float e = 0.f;
    #pragma unroll
    for (int d = 0; d < 8; d++) e += qr[d * 96 + w] * kr[d * 96 + kp];
    ew[w * 97 + kp] = e;
  }
  __syncthreads();
  int lane = tid & 63, wvid = tid >> 6;
  for (int w = wvid; w < 96; w += 4){
    float* eb = ebuf + (((size_t)b * 96 + w) * 96 + h) * 96;
    float x0 = eb[lane];
    float x1 = (lane < 32) ? eb[64 + lane] : ew[w * 97 + (lane - 32)];
    float x2 = ew[w * 97 + (lane + 32)];
    float mx = fmaxf(x0, fmaxf(x1, x2));
    #pragma unroll
    for (int s = 32; s; s >>= 1) mx = fmaxf(mx, __shfl_xor(mx, s));
    float e0 = __expf(x0 - mx), e1 = __expf(x1 - mx), e2 = __expf(x2 - mx);
    float sm = e0 + e1 + e2;
    #pragma unroll
    for (int s = 32; s; s >>= 1) sm += __shfl_xor(sm, s);
    float inv = 1.f / sm;
    eb[lane] = e0 * inv;
    if (lane < 32) eb[64 + lane] = e1 * inv; else ew[w * 97 + (lane - 32)] = e1 * inv;
    ew[w * 97 + (lane + 32)] = e2 * inv;
  }
  __syncthreads();
  float gm = gamma[0];
  for (int i = tid; i < 6144; i += 256){
    int d = i / 96, w = i - d * 96;
    float o = 0.f;
    #pragma unroll 4
    for (int kp = 0; kp < 96; kp++) o += ew[w * 97 + kp] * bf2f(vr[d * 96 + kp]);
    size_t idx = ((size_t)b * 64 + d) * HW + h * 96 + w;
    xout[idx] = xin[idx] + gm * o;
  }
}

// ---------------- CCA: column kernel — oH, final accumulate ----------------
__global__ __launch_bounds__(256) void cca_colO_kernel(const float* __restrict__ v,
    const float* __restrict__ gamma, const float* __restrict__ ebuf, float* __restrict__ xout){
  int blk = blockIdx.x; int b = blk / 96, w = blk - b * 96;
  __shared__ float vc[6144];   // [64][96]
  __shared__ float aH[9312];   // [96][97]
  int tid = threadIdx.x;
  for (int i = tid; i < 6144; i += 256){
    int d = i / 96, hp = i - d * 96;
    vc[i] = v[((size_t)b * 64 + d) * HW + hp * 96 + w];
  }
  const float* eb = ebuf + ((size_t)b * 96 + w) * HW;
  for (int i = tid; i < 9216; i += 256){
    int hh = i / 96, kp = i - hh * 96;
    aH[hh * 97 + kp] = eb[i];
  }
  __syncthreads();
  float gm = gamma[0];
  for (int i = tid; i < 6144; i += 256){
    int d = i / 96, hh = i - d * 96;
    float o = 0.f;
    #pragma unroll 4
    for (int kp = 0; kp < 96; kp++) o += aH[hh * 97 + kp] * vc[d * 96 + kp];
    size_t idx = ((size_t)b * 64 + d) * HW + hh * 96 + w;
    xout[idx] += gm * o;
  }
}

// ---------------- cls2 1x1 conv 64->19 at low res (commutes with upsample) ----------------
__global__ __launch_bounds__(256) void cls2_kernel(const float* __restrict__ y,
    const float* __restrict__ w2, float* __restrict__ t19){
  __shared__ float w2L[19 * 64];
  int tid = threadIdx.x;
  for (int i = tid; i < 19 * 64; i += 256) w2L[i] = w2[i];
  __syncthreads();
  int gp = blockIdx.x * 256 + tid;
  int b = gp / HW, pos = gp - b * HW;
  float acc[19];
  #pragma unroll
  for (int o = 0; o < 19; o++) acc[o] = 0.f;
  const float* yb = y + (size_t)b * 64 * HW + pos;
  #pragma unroll 4
  for (int c = 0; c < 64; c++){
    float xv = yb[(size_t)c * HW];
    #pragma unroll
    for (int o = 0; o < 19; o++) acc[o] += w2L[o * 64 + c] * xv;
  }
  #pragma unroll
  for (int o = 0; o < 19; o++) t19[((size_t)b * 19 + o) * HW + pos] = acc[o];
}

// ---------------- bilinear x8 upsample (align_corners) of 19ch ----------------
__global__ void upsample_kernel(const float* __restrict__ t19, float* __restrict__ out){
  int gid = blockIdx.x * 256 + threadIdx.x;
  int xq = gid % 192; int t = gid / 192;
  int yy = t % 768; t /= 768;
  int o = t % 19; int b = t / 19;
  const float R = 95.0f / 767.0f;
  float ry = yy * R;
  int iy = (int)ry;
  float fy = ry - (float)iy;
  int iy1 = min(iy + 1, 95);
  const float* base = t19 + ((size_t)b * 19 + o) * HW;
  float4 res;
  float* rp = (float*)&res;
  #pragma unroll
  for (int j = 0; j < 4; j++){
    int xx = xq * 4 + j;
    float rx = xx * R;
    int ix = (int)rx; float fx = rx - (float)ix; int ix1 = min(ix + 1, 95);
    float v00 = base[iy * 96 + ix],  v01 = base[iy * 96 + ix1];
    float v10 = base[iy1 * 96 + ix], v11 = base[iy1 * 96 + ix1];
    rp[j] = (1.f - fy) * ((1.f - fx) * v00 + fx * v01) + fy * ((1.f - fx) * v10 + fx * v11);
  }
  *(float4*)(out + (((size_t)b * 19 + o) * 768 + yy) * 768 + xq * 4) = res;
}

// ---------------- host-side orchestration ----------------
extern "C" void kernel_launch(void* const* d_in, const int* in_sizes, int n_in,
                              void* d_out, int out_size, void* d_ws, size_t ws_size,
                              hipStream_t stream){
  const float* x       = (const float*)d_in[0];
  const float* w_in    = (const float*)d_in[1];
  const float* bn_in_g = (const float*)d_in[2];
  const float* bn_in_b = (const float*)d_in[3];
  const float* bn_in_m = (const float*)d_in[4];
  const float* bn_in_v = (const float*)d_in[5];
  const float* wq      = (const float*)d_in[6];
  const float* wk      = (const float*)d_in[7];
  const float* wv      = (const float*)d_in[8];
  const float* gamma   = (const float*)d_in[9];
  const float* w_out   = (const float*)d_in[10];
  const float* bn_o_g  = (const float*)d_in[11];
  const float* bn_o_b  = (const float*)d_in[12];
  const float* bn_o_m  = (const float*)d_in[13];
  const float* bn_o_v  = (const float*)d_in[14];
  const float* w_cls1  = (const float*)d_in[15];
  const float* bn_c_g  = (const float*)d_in[16];
  const float* bn_c_b  = (const float*)d_in[17];
  const float* bn_c_m  = (const float*)d_in[18];
  const float* bn_c_v  = (const float*)d_in[19];
  const float* w_cls2  = (const float*)d_in[20];
  float* out = (float*)d_out;

  char* ws = (char*)d_ws;
  size_t off = 0;
  auto alloc = [&](size_t bytes) -> void* {
    void* p = ws + off; off += (bytes + 255) & ~(size_t)255; return p;
  };
  const size_t NCHWf = (size_t)2 * 64 * HW * 4;          // 4.72 MB
  float* accum = (float*)alloc(NCHWf);
  float* xattA = (float*)alloc(NCHWf);
  float* xattB = (float*)alloc(NCHWf);
  float* mid   = (float*)alloc(NCHWf);
  float* ybuf  = (float*)alloc(NCHWf);
  float* qb    = (float*)alloc((size_t)2 * 8 * HW * 4);
  float* kb    = (float*)alloc((size_t)2 * 8 * HW * 4);
  float* vb    = (float*)alloc(NCHWf);
  float* ebuf  = (float*)alloc((size_t)2 * 96 * HW * 4); // 7.08 MB
  float* t19   = (float*)alloc((size_t)2 * 19 * HW * 4);
  unsigned short* WpIn  = (unsigned short*)alloc((size_t)64 * 2048 * 9 * 2);
  unsigned short* WpOut = (unsigned short*)alloc((size_t)64 * 64 * 9 * 2);
  unsigned short* WpCls = (unsigned short*)alloc((size_t)64 * 2112 * 9 * 2);
  (void)ws_size; (void)in_sizes; (void)n_in; (void)out_size;

  // weight packs (bf16, [ck][tap][o][c] coalesced-B layout)
  packw_kernel<<<1024, 256, 0, stream>>>(w_in,   WpIn,  2048);
  packw_kernel<<<64,   256, 0, stream>>>(w_out,  WpOut, 64);
  packw_kernel<<<1024, 256, 0, stream>>>(w_cls1, WpCls, 2112);

  // conv_in (2048 -> 64) + BN + ReLU
  hipMemsetAsync(accum, 0, NCHWf, stream);
  conv3x3_kernel<<<dim3(144, 8), 256, 0, stream>>>(x, nullptr, 64, WpIn, accum, 64);
  bn_act_kernel<<<4608, 256, 0, stream>>>(accum, xattA, bn_in_g, bn_in_b, bn_in_m, bn_in_v, 1);

  // CCA pass 1: xattA -> xattB
  cca_proj_kernel<<<144, 128, 0, stream>>>(xattA, wq, wk, wv, qb, kb, vb);
  cca_colE_kernel<<<192, 256, 0, stream>>>(qb, kb, ebuf);
  cca_rowSM_kernel<<<192, 256, 0, stream>>>(qb, kb, vb, xattA, gamma, ebuf, xattB);
  cca_colO_kernel<<<192, 256, 0, stream>>>(vb, gamma, ebuf, xattB);
  // CCA pass 2: xattB -> xattA
  cca_proj_kernel<<<144, 128, 0, stream>>>(xattB, wq, wk, wv, qb, kb, vb);
  cca_colE_kernel<<<192, 256, 0, stream>>>(qb, kb, ebuf);
  cca_rowSM_kernel<<<192, 256, 0, stream>>>(qb, kb, vb, xattB, gamma, ebuf, xattA);
  cca_colO_kernel<<<192, 256, 0, stream>>>(vb, gamma, ebuf, xattA);

  // conv_out (64 -> 64) + BN + ReLU
  hipMemsetAsync(accum, 0, NCHWf, stream);
  conv3x3_kernel<<<dim3(144, 2), 256, 0, stream>>>(xattA, nullptr, 2, WpOut, accum, 2);
  bn_act_kernel<<<4608, 256, 0, stream>>>(accum, mid, bn_o_g, bn_o_b, bn_o_m, bn_o_v, 1);

  // cls1 conv on concat([x, mid]) (2112 -> 64) + BN (no relu)
  hipMemsetAsync(accum, 0, NCHWf, stream);
  conv3x3_kernel<<<dim3(144, 8), 256, 0, stream>>>(x, mid, 64, WpCls, accum, 66);
  bn_act_kernel<<<4608, 256, 0, stream>>>(accum, ybuf, bn_c_g, bn_c_b, bn_c_m, bn_c_v, 0);

  // cls2 (1x1, 64->19) at 96x96, then bilinear x8 upsample (commuted with 1x1 conv)
  cls2_kernel<<<72, 256, 0, stream>>>(ybuf, w_cls2, t19);
  upsample_kernel<<<21888, 256, 0, stream>>>(t19, out);
}

// Round 3
// 688.498 us; speedup vs baseline: 1.4283x; 1.2343x over previous
//
#include <hip/hip_runtime.h>
#include <stdint.h>

#define HW 9216   // 96*96

typedef float f32x4 __attribute__((ext_vector_type(4)));
typedef short s16x8 __attribute__((ext_vector_type(8)));

__device__ __forceinline__ unsigned short f2bf(float f){
  union { float fv; uint32_t u; } x; x.fv = f;
  uint32_t u = x.u;
  u += 0x7fffu + ((u >> 16) & 1u);   // RNE
  return (unsigned short)(u >> 16);
}
__device__ __forceinline__ float bf2f(unsigned short s){
  union { uint32_t u; float fv; } x; x.u = ((uint32_t)s) << 16;
  return x.fv;
}

__device__ __forceinline__ void gload16(const void* g, void* l){
  __builtin_amdgcn_global_load_lds(
    (const __attribute__((address_space(1))) unsigned int*)g,
    (__attribute__((address_space(3))) unsigned int*)l, 16, 0, 0);
}

// ---------------- NCHW f32 -> NHWC bf16 transpose (x only) ----------------
// block: 64 px x 256 ch tile. grid = 2b * 8cchunk * 144pxtile
__global__ __launch_bounds__(256) void transp_kernel(const float* __restrict__ x,
    unsigned short* __restrict__ xT){
  __shared__ unsigned short tl[256 * 66];   // [cc][px] pad 66
  int blk = blockIdx.x;
  int b = blk / 1152; int r = blk - b * 1152;
  int cchunk = r / 144, pxt = r - cchunk * 144;
  int c0 = cchunk * 256, px0 = pxt * 64;
  int tid = threadIdx.x;
  for (int e = tid; e < 16384; e += 256){
    int cc = e >> 6, px = e & 63;
    tl[cc * 66 + px] = f2bf(x[((size_t)(b * 2048 + c0 + cc)) * HW + px0 + px]);
  }
  __syncthreads();
  for (int j = tid; j < 2048; j += 256){
    int px = j >> 5, oct = j & 31;
    s16x8 pk;
    #pragma unroll
    for (int t = 0; t < 8; t++) pk[t] = (short)tl[(oct * 8 + t) * 66 + px];
    *(s16x8*)(xT + ((size_t)(b * 9216 + px0 + px)) * 2048 + c0 + oct * 8) = pk;
  }
}

// ---------------- weight pack: Wp[((ck*9 + tap)*64 + o)*32 + c] ----------------
__global__ void packw_kernel(const float* __restrict__ w, unsigned short* __restrict__ Wp, int Cin){
  int total = 64 * Cin * 9;
  for (int i = blockIdx.x * blockDim.x + threadIdx.x; i < total; i += gridDim.x * blockDim.x){
    int c = i & 31; int r = i >> 5; int o = r & 63; int r2 = r >> 6;
    int tap = r2 % 9; int ck = r2 / 9;
    Wp[i] = f2bf(w[((size_t)o * Cin + ck * 32 + c) * 9 + tap]);
  }
}

// ---------------- conv3x3 NHWC implicit GEMM: tile 16x16 px, N=64, bf16 MFMA ----------------
// A staged via global_load_lds (pre-swizzled source quad, linear LDS dest),
// B direct from L2, K-split writes private bf16 slices [ks][mt][m][o].
__global__ __launch_bounds__(256) void conv_nhwc_kernel(
    const unsigned short* __restrict__ A0, int c0stride,
    const unsigned short* __restrict__ A1, int nck0,
    const unsigned short* __restrict__ Wp,
    unsigned short* __restrict__ sl, int nchunks,
    const unsigned short* __restrict__ zp){
  int mt = blockIdx.x;
  int b = mt / 36; int r = mt - b * 36;
  int h0 = (r / 6) * 16, w0 = (r % 6) * 16;
  int KS = gridDim.y, ks = blockIdx.y;
  int c0 = (nchunks * ks) / KS, c1 = (nchunks * (ks + 1)) / KS;
  int tid = threadIdx.x, lane = tid & 63, wv = tid >> 6;
  int ln = lane & 15, kg = lane >> 4;
  __shared__ char halo[2][20736];   // 324 px * 64B, quad-XOR swizzled

  // per-item staging precompute (item i = tid + rr*256, 1296 items = 324px * 4 quads)
  int pixb0[6], pixb1[6]; bool val[6];
  #pragma unroll
  for (int rr = 0; rr < 6; rr++){
    int i = tid + rr * 256;
    int p = i >> 2, q_lds = i & 3;
    int logq = q_lds ^ (p & 3);
    int hh = p / 18, ww = p - hh * 18;
    int h = h0 - 1 + hh, w = w0 - 1 + ww;
    bool v = (i < 1296) && ((unsigned)h < 96u) && ((unsigned)w < 96u);
    val[rr] = v;
    int pix = (b * 96 + h) * 96 + w;
    pixb0[rr] = v ? (pix * c0stride * 2 + logq * 16) : 0;
    pixb1[rr] = v ? (pix * 128 + logq * 16) : 0;
  }
  const char* a0B = (const char*)A0;
  const char* a1B = (const char*)A1;
  const char* zpB = (const char*)zp;

  auto stage = [&](int buf, int ck){
    bool inA0 = (ck < nck0);
    int chb0 = ck * 64, chb1 = (ck - nck0) * 64;
    char* ldsB = &halo[buf][0];
    #pragma unroll
    for (int rr = 0; rr < 6; rr++){
      int i = tid + rr * 256;
      if (i < 1296){
        const char* src = zpB;
        if (val[rr]) src = inA0 ? (a0B + pixb0[rr] + chb0) : (a1B + pixb1[rr] + chb1);
        gload16(src, ldsB + i * 16);
      }
    }
  };

  f32x4 acc[4][4];
  #pragma unroll
  for (int i = 0; i < 4; i++)
    #pragma unroll
    for (int j = 0; j < 4; j++) acc[i][j] = (f32x4)(0.f);

  stage(0, c0);
  __syncthreads();

  for (int ck = c0; ck < c1; ck++){
    int cur = (ck - c0) & 1;
    if (ck + 1 < c1) stage(cur ^ 1, ck + 1);
    const unsigned short* wb = Wp + (size_t)ck * 18432 + ln * 32 + kg * 8;
    const char* hb = &halo[cur][0];
    #pragma unroll 1
    for (int tap = 0; tap < 9; tap++){
      int dy = tap / 3, dx = tap - dy * 3;
      s16x8 bf[4];
      #pragma unroll
      for (int nf = 0; nf < 4; nf++) bf[nf] = *(const s16x8*)(wb + tap * 2048 + nf * 512);
      #pragma unroll
      for (int mf = 0; mf < 4; mf++){
        int p = (wv * 4 + mf + dy) * 18 + (ln + dx);
        int aoff = p * 64 + ((kg ^ (p & 3)) << 4);
        s16x8 a = *(const s16x8*)(hb + aoff);
        #pragma unroll
        for (int nf = 0; nf < 4; nf++)
          acc[mf][nf] = __builtin_amdgcn_mfma_f32_16x16x32_bf16(a, bf[nf], acc[mf][nf], 0, 0, 0);
      }
    }
    __syncthreads();
  }

  unsigned short* base = sl + ((size_t)(ks * 72 + mt)) * 16384;
  #pragma unroll
  for (int mf = 0; mf < 4; mf++)
    #pragma unroll
    for (int nf = 0; nf < 4; nf++){
      int o = nf * 16 + ln;
      #pragma unroll
      for (int rr = 0; rr < 4; rr++){
        int m = wv * 64 + mf * 16 + kg * 4 + rr;
        base[m * 64 + o] = f2bf(acc[mf][nf][rr]);
      }
    }
}

// ---------------- K-split reduce + BN (+ReLU) -> NHWC bf16 ----------------
__global__ __launch_bounds__(256) void bn_reduce_kernel(const unsigned short* __restrict__ sl,
    int KS, const float* __restrict__ g, const float* __restrict__ bb,
    const float* __restrict__ mm, const float* __restrict__ vv, int relu,
    unsigned short* __restrict__ out){
  int idx = blockIdx.x * 256 + threadIdx.x;
  int mt = idx >> 14, e = idx & 16383;
  int m = e >> 6, o = e & 63;
  float s = 0.f;
  for (int ks = 0; ks < KS; ks++) s += bf2f(sl[((size_t)(ks * 72 + mt)) * 16384 + e]);
  float sc = g[o] * rsqrtf(vv[o] + 1e-5f);
  float valf = (s - mm[o]) * sc + bb[o];
  if (relu) valf = fmaxf(valf, 0.f);
  int b = mt / 36; int r = mt - b * 36;
  int h = (r / 6) * 16 + (m >> 4), w = (r % 6) * 16 + (m & 15);
  out[(((size_t)b * 96 + h) * 96 + w) * 64 + o] = f2bf(valf);
}

// ---------------- CCA: q,k,v projections (1x1) — NHWC bf16 input ----------------
__global__ __launch_bounds__(128) void cca_proj_kernel(const unsigned short* __restrict__ xin,
    const float* __restrict__ wq, const float* __restrict__ wk, const float* __restrict__ wv,
    float* __restrict__ q, float* __restrict__ k, float* __restrict__ v){
  __shared__ float wqL[512], wkL[512], wvL[4096];
  int tid = threadIdx.x;
  for (int i = tid; i < 512; i += 128){ wqL[i] = wq[i]; wkL[i] = wk[i]; }
  for (int i = tid; i < 4096; i += 128) wvL[i] = wv[i];
  __syncthreads();
  int gp = blockIdx.x * 128 + tid;
  int b = gp / HW, pos = gp - b * HW;
  unsigned short xv16[64];
  #pragma unroll
  for (int t = 0; t < 8; t++)
    *(s16x8*)(&xv16[t * 8]) = *(const s16x8*)(xin + (size_t)gp * 64 + t * 8);
  float qa[8], ka[8], va[64];
  #pragma unroll
  for (int d = 0; d < 8; d++){ qa[d] = 0.f; ka[d] = 0.f; }
  #pragma unroll
  for (int d = 0; d < 64; d++) va[d] = 0.f;
  #pragma unroll 4
  for (int c = 0; c < 64; c++){
    float xv = bf2f(xv16[c]);
    #pragma unroll
    for (int d = 0; d < 8; d++){ qa[d] += wqL[d * 64 + c] * xv; ka[d] += wkL[d * 64 + c] * xv; }
    #pragma unroll
    for (int d = 0; d < 64; d++) va[d] += wvL[d * 64 + c] * xv;
  }
  #pragma unroll
  for (int d = 0; d < 8; d++){
    q[((size_t)b * 8 + d) * HW + pos] = qa[d];
    k[((size_t)b * 8 + d) * HW + pos] = ka[d];
  }
  #pragma unroll
  for (int d = 0; d < 64; d++) v[((size_t)b * 64 + d) * HW + pos] = va[d];
}

// ---------------- CCA: column energies eH (with diagonal mask) ----------------
__global__ __launch_bounds__(256) void cca_colE_kernel(const float* __restrict__ q,
    const float* __restrict__ k, float* __restrict__ ebuf){
  int blk = blockIdx.x; int b = blk / 96, w = blk - b * 96;
  __shared__ float qc[768], kc[768];
  int tid = threadIdx.x;
  for (int i = tid; i < 768; i += 256){
    int d = i / 96, hp = i - d * 96;
    qc[i] = q[((size_t)b * 8 + d) * HW + hp * 96 + w];
    kc[i] = k[((size_t)b * 8 + d) * HW + hp * 96 + w];
  }
  __syncthreads();
  float* eb = ebuf + ((size_t)b * 96 + w) * HW;
  for (int i = tid; i < 9216; i += 256){
    int h = i / 96, kp = i - h * 96;
    float e = 0.f;
    #pragma unroll
    for (int d = 0; d < 8; d++) e += qc[d * 96 + h] * kc[d * 96 + kp];
    eb[i] = (kp == h) ? -1e30f : e;
  }
}

// ---------------- CCA: row kernel — eW, joint softmax, oW partial (NHWC bf16 io) ----------------
__global__ __launch_bounds__(256) void cca_rowSM_kernel(const float* __restrict__ q,
    const float* __restrict__ k, const float* __restrict__ v,
    const unsigned short* __restrict__ xin, const float* __restrict__ gamma,
    float* __restrict__ ebuf, unsigned short* __restrict__ xout){
  int blk = blockIdx.x; int b = blk / 96, h = blk - b * 96;
  __shared__ float qr[768], kr[768];
  __shared__ unsigned short vr[64 * 98];   // pad 98
  __shared__ float ew[9312];               // [96][97]
  int tid = threadIdx.x;
  for (int i = tid; i < 768; i += 256){
    int d = i / 96, wp = i - d * 96;
    qr[i] = q[((size_t)b * 8 + d) * HW + h * 96 + wp];
    kr[i] = k[((size_t)b * 8 + d) * HW + h * 96 + wp];
  }
  for (int i = tid; i < 6144; i += 256){
    int d = i / 96, wp = i - d * 96;
    vr[d * 98 + wp] = f2bf(v[((size_t)b * 64 + d) * HW + h * 96 + wp]);
  }
  __syncthreads();
  for (int i = tid; i < 9216; i += 256){
    int w = i / 96, kp = i - w * 96;
    float e = 0.f;
    #pragma unroll
    for (int d = 0; d < 8; d++) e += qr[d * 96 + w] * kr[d * 96 + kp];
    ew[w * 97 + kp] = e;
  }
  __syncthreads();
  int lane = tid & 63, wvid = tid >> 6;
  for (int w = wvid; w < 96; w += 4){
    float* eb = ebuf + (((size_t)b * 96 + w) * 96 + h) * 96;
    float x0 = eb[lane];
    float x1 = (lane < 32) ? eb[64 + lane] : ew[w * 97 + (lane - 32)];
    float x2 = ew[w * 97 + (lane + 32)];
    float mx = fmaxf(x0, fmaxf(x1, x2));
    #pragma unroll
    for (int s = 32; s; s >>= 1) mx = fmaxf(mx, __shfl_xor(mx, s));
    float e0 = __expf(x0 - mx), e1 = __expf(x1 - mx), e2 = __expf(x2 - mx);
    float sm = e0 + e1 + e2;
    #pragma unroll
    for (int s = 32; s; s >>= 1) sm += __shfl_xor(sm, s);
    float inv = 1.f / sm;
    eb[lane] = e0 * inv;
    if (lane < 32) eb[64 + lane] = e1 * inv; else ew[w * 97 + (lane - 32)] = e1 * inv;
    ew[w * 97 + (lane + 32)] = e2 * inv;
  }
  __syncthreads();
  float gm = gamma[0];
  for (int i = tid; i < 6144; i += 256){
    int w = i >> 6, d = i & 63;
    float o = 0.f;
    #pragma unroll 4
    for (int kp = 0; kp < 96; kp++) o += ew[w * 97 + kp] * bf2f(vr[d * 98 + kp]);
    size_t pix = ((size_t)b * 96 + h) * 96 + w;
    float xr = bf2f(xin[pix * 64 + d]);
    xout[pix * 64 + d] = f2bf(xr + gm * o);
  }
}

// ---------------- CCA: column kernel — oH + final accumulate (NHWC bf16 io) ----------------
__global__ __launch_bounds__(256) void cca_colO_kernel(const float* __restrict__ v,
    const float* __restrict__ gamma, const float* __restrict__ ebuf,
    const unsigned short* __restrict__ xpart, unsigned short* __restrict__ xout){
  int blk = blockIdx.x; int b = blk / 96, w = blk - b * 96;
  __shared__ float vc[64 * 97];   // pad 97
  __shared__ float aH[9312];      // [96][97]
  int tid = threadIdx.x;
  for (int i = tid; i < 6144; i += 256){
    int d = i / 96, hp = i - d * 96;
    vc[d * 97 + hp] = v[((size_t)b * 64 + d) * HW + hp * 96 + w];
  }
  const float* eb = ebuf + ((size_t)b * 96 + w) * HW;
  for (int i = tid; i < 9216; i += 256){
    int hh = i / 96, kp = i - hh * 96;
    aH[hh * 97 + kp] = eb[i];
  }
  __syncthreads();
  float gm = gamma[0];
  for (int i = tid; i < 6144; i += 256){
    int hh = i >> 6, d = i & 63;
    float o = 0.f;
    #pragma unroll 4
    for (int kp = 0; kp < 96; kp++) o += aH[hh * 97 + kp] * vc[d * 97 + kp];
    size_t pix = ((size_t)b * 96 + hh) * 96 + w;
    float xr = bf2f(xpart[pix * 64 + d]);
    xout[pix * 64 + d] = f2bf(xr + gm * o);
  }
}

// ---------------- cls2 1x1 conv 64->19 at low res (NHWC bf16 input) ----------------
__global__ __launch_bounds__(256) void cls2_kernel(const unsigned short* __restrict__ y,
    const float* __restrict__ w2, float* __restrict__ t19){
  __shared__ float w2L[19 * 64];
  int tid = threadIdx.x;
  for (int i = tid; i < 19 * 64; i += 256) w2L[i] = w2[i];
  __syncthreads();
  int gp = blockIdx.x * 256 + tid;
  int b = gp / HW, pos = gp - b * HW;
  unsigned short xv16[64];
  #pragma unroll
  for (int t = 0; t < 8; t++)
    *(s16x8*)(&xv16[t * 8]) = *(const s16x8*)(y + (size_t)gp * 64 + t * 8);
  float acc[19];
  #pragma unroll
  for (int o = 0; o < 19; o++) acc[o] = 0.f;
  #pragma unroll 4
  for (int c = 0; c < 64; c++){
    float xv = bf2f(xv16[c]);
    #pragma unroll
    for (int o = 0; o < 19; o++) acc[o] += w2L[o * 64 + c] * xv;
  }
  #pragma unroll
  for (int o = 0; o < 19; o++) t19[((size_t)b * 19 + o) * HW + pos] = acc[o];
}

// ---------------- bilinear x8 upsample (align_corners) of 19ch ----------------
__global__ void upsample_kernel(const float* __restrict__ t19, float* __restrict__ out){
  int gid = blockIdx.x * 256 + threadIdx.x;
  int xq = gid % 192; int t = gid / 192;
  int yy = t % 768; t /= 768;
  int o = t % 19; int b = t / 19;
  const float R = 95.0f / 767.0f;
  float ry = yy * R;
  int iy = (int)ry;
  float fy = ry - (float)iy;
  int iy1 = min(iy + 1, 95);
  const float* base = t19 + ((size_t)b * 19 + o) * HW;
  float4 res;
  float* rp = (float*)&res;
  #pragma unroll
  for (int j = 0; j < 4; j++){
    int xx = xq * 4 + j;
    float rx = xx * R;
    int ix = (int)rx; float fx = rx - (float)ix; int ix1 = min(ix + 1, 95);
    float v00 = base[iy * 96 + ix],  v01 = base[iy * 96 + ix1];
    float v10 = base[iy1 * 96 + ix], v11 = base[iy1 * 96 + ix1];
    rp[j] = (1.f - fy) * ((1.f - fx) * v00 + fx * v01) + fy * ((1.f - fx) * v10 + fx * v11);
  }
  *(float4*)(out + (((size_t)b * 19 + o) * 768 + yy) * 768 + xq * 4) = res;
}

// ---------------- host-side orchestration ----------------
extern "C" void kernel_launch(void* const* d_in, const int* in_sizes, int n_in,
                              void* d_out, int out_size, void* d_ws, size_t ws_size,
                              hipStream_t stream){
  const float* x       = (const float*)d_in[0];
  const float* w_in    = (const float*)d_in[1];
  const float* bn_in_g = (const float*)d_in[2];
  const float* bn_in_b = (const float*)d_in[3];
  const float* bn_in_m = (const float*)d_in[4];
  const float* bn_in_v = (const float*)d_in[5];
  const float* wq      = (const float*)d_in[6];
  const float* wk      = (const float*)d_in[7];
  const float* wv      = (const float*)d_in[8];
  const float* gamma   = (const float*)d_in[9];
  const float* w_out   = (const float*)d_in[10];
  const float* bn_o_g  = (const float*)d_in[11];
  const float* bn_o_b  = (const float*)d_in[12];
  const float* bn_o_m  = (const float*)d_in[13];
  const float* bn_o_v  = (const float*)d_in[14];
  const float* w_cls1  = (const float*)d_in[15];
  const float* bn_c_g  = (const float*)d_in[16];
  const float* bn_c_b  = (const float*)d_in[17];
  const float* bn_c_m  = (const float*)d_in[18];
  const float* bn_c_v  = (const float*)d_in[19];
  const float* w_cls2  = (const float*)d_in[20];
  float* out = (float*)d_out;

  char* ws = (char*)d_ws;
  size_t off = 0;
  auto alloc = [&](size_t bytes) -> void* {
    void* p = ws + off; off += (bytes + 255) & ~(size_t)255; return p;
  };
  const size_t NHWCb = (size_t)2 * HW * 64 * 2;                 // 2.36 MB
  unsigned short* xT   = (unsigned short*)alloc((size_t)2 * HW * 2048 * 2);  // 75.5 MB
  unsigned short* sl   = (unsigned short*)alloc((size_t)8 * 72 * 16384 * 2); // 18.9 MB (also ebuf)
  float* ebuf = (float*)sl;                                     // CCA-phase reuse
  unsigned short* xattA = (unsigned short*)alloc(NHWCb);
  unsigned short* xattB = (unsigned short*)alloc(NHWCb);
  unsigned short* Ptmp  = (unsigned short*)alloc(NHWCb);
  unsigned short* attT  = (unsigned short*)alloc(NHWCb);
  unsigned short* midT  = (unsigned short*)alloc(NHWCb);
  unsigned short* ybuf  = (unsigned short*)alloc(NHWCb);
  float* qb    = (float*)alloc((size_t)2 * 8 * HW * 4);
  float* kb    = (float*)alloc((size_t)2 * 8 * HW * 4);
  float* vb    = (float*)alloc((size_t)2 * 64 * HW * 4);
  float* t19   = (float*)alloc((size_t)2 * 19 * HW * 4);
  unsigned short* WpIn  = (unsigned short*)alloc((size_t)64 * 2048 * 9 * 2);
  unsigned short* WpOut = (unsigned short*)alloc((size_t)64 * 64 * 9 * 2);
  unsigned short* WpCls = (unsigned short*)alloc((size_t)64 * 2112 * 9 * 2);
  unsigned short* zp    = (unsigned short*)alloc(256);
  (void)ws_size; (void)in_sizes; (void)n_in; (void)out_size;

  hipMemsetAsync(zp, 0, 256, stream);
  transp_kernel<<<2304, 256, 0, stream>>>(x, xT);
  packw_kernel<<<1024, 256, 0, stream>>>(w_in,   WpIn,  2048);
  packw_kernel<<<64,   256, 0, stream>>>(w_out,  WpOut, 64);
  packw_kernel<<<1024, 256, 0, stream>>>(w_cls1, WpCls, 2112);

  // conv_in (2048 -> 64) + BN + ReLU -> xattA (NHWC bf16)
  conv_nhwc_kernel<<<dim3(72, 8), 256, 0, stream>>>(xT, 2048, nullptr, 64, WpIn, sl, 64, zp);
  bn_reduce_kernel<<<4608, 256, 0, stream>>>(sl, 8, bn_in_g, bn_in_b, bn_in_m, bn_in_v, 1, xattA);

  // CCA pass 1: xattA -> xattB
  cca_proj_kernel<<<144, 128, 0, stream>>>(xattA, wq, wk, wv, qb, kb, vb);
  cca_colE_kernel<<<192, 256, 0, stream>>>(qb, kb, ebuf);
  cca_rowSM_kernel<<<192, 256, 0, stream>>>(qb, kb, vb, xattA, gamma, ebuf, Ptmp);
  cca_colO_kernel<<<192, 256, 0, stream>>>(vb, gamma, ebuf, Ptmp, xattB);
  // CCA pass 2: xattB -> attT
  cca_proj_kernel<<<144, 128, 0, stream>>>(xattB, wq, wk, wv, qb, kb, vb);
  cca_colE_kernel<<<192, 256, 0, stream>>>(qb, kb, ebuf);
  cca_rowSM_kernel<<<192, 256, 0, stream>>>(qb, kb, vb, xattB, gamma, ebuf, Ptmp);
  cca_colO_kernel<<<192, 256, 0, stream>>>(vb, gamma, ebuf, Ptmp, attT);

  // conv_out (64 -> 64) + BN + ReLU -> midT
  conv_nhwc_kernel<<<dim3(72, 2), 256, 0, stream>>>(attT, 64, nullptr, 2, WpOut, sl, 2, zp);
  bn_reduce_kernel<<<4608, 256, 0, stream>>>(sl, 2, bn_o_g, bn_o_b, bn_o_m, bn_o_v, 1, midT);

  // cls1 conv on concat([x, mid]) (2112 -> 64) + BN -> ybuf
  conv_nhwc_kernel<<<dim3(72, 8), 256, 0, stream>>>(xT, 2048, midT, 64, WpCls, sl, 66, zp);
  bn_reduce_kernel<<<4608, 256, 0, stream>>>(sl, 8, bn_c_g, bn_c_b, bn_c_m, bn_c_v, 0, ybuf);

  // cls2 (1x1, 64->19) at 96x96, then bilinear x8 upsample
  cls2_kernel<<<72, 256, 0, stream>>>(ybuf, w_cls2, t19);
  upsample_kernel<<<21888, 256, 0, stream>>>(t19, out);
}

// Round 4
// 523.100 us; speedup vs baseline: 1.8798x; 1.3162x over previous
//
#include <hip/hip_runtime.h>
#include <stdint.h>

#define HW 9216   // 96*96

typedef float f32x4 __attribute__((ext_vector_type(4)));
typedef short s16x8 __attribute__((ext_vector_type(8)));

__device__ __forceinline__ unsigned short f2bf(float f){
  union { float fv; uint32_t u; } x; x.fv = f;
  uint32_t u = x.u;
  u += 0x7fffu + ((u >> 16) & 1u);   // RNE
  return (unsigned short)(u >> 16);
}
__device__ __forceinline__ float bf2f(unsigned short s){
  union { uint32_t u; float fv; } x; x.u = ((uint32_t)s) << 16;
  return x.fv;
}

__device__ __forceinline__ void gload16(const void* g, void* l){
  __builtin_amdgcn_global_load_lds(
    (const __attribute__((address_space(1))) unsigned int*)g,
    (__attribute__((address_space(3))) unsigned int*)l, 16, 0, 0);
}

// ---------------- NCHW f32 -> NHWC bf16 transpose (x only) ----------------
__global__ __launch_bounds__(256) void transp_kernel(const float* __restrict__ x,
    unsigned short* __restrict__ xT){
  __shared__ unsigned short tl[256 * 66];   // [cc][px] pad 66
  int blk = blockIdx.x;
  int b = blk / 1152; int r = blk - b * 1152;
  int cchunk = r / 144, pxt = r - cchunk * 144;
  int c0 = cchunk * 256, px0 = pxt * 64;
  int tid = threadIdx.x;
  for (int e = tid; e < 16384; e += 256){
    int cc = e >> 6, px = e & 63;
    tl[cc * 66 + px] = f2bf(x[((size_t)(b * 2048 + c0 + cc)) * HW + px0 + px]);
  }
  __syncthreads();
  for (int j = tid; j < 2048; j += 256){
    int px = j >> 5, oct = j & 31;
    s16x8 pk;
    #pragma unroll
    for (int t = 0; t < 8; t++) pk[t] = (short)tl[(oct * 8 + t) * 66 + px];
    *(s16x8*)(xT + ((size_t)(b * 9216 + px0 + px)) * 2048 + c0 + oct * 8) = pk;
  }
}

// ---------------- weight pack: Wp[((ck*9 + tap)*64 + o)*32 + c] ----------------
__global__ void packw_kernel(const float* __restrict__ w, unsigned short* __restrict__ Wp, int Cin){
  int total = 64 * Cin * 9;
  for (int i = blockIdx.x * blockDim.x + threadIdx.x; i < total; i += gridDim.x * blockDim.x){
    int c = i & 31; int r = i >> 5; int o = r & 63; int r2 = r >> 6;
    int tap = r2 % 9; int ck = r2 / 9;
    Wp[i] = f2bf(w[((size_t)o * Cin + ck * 32 + c) * 9 + tap]);
  }
}

// ---------------- conv3x3 NHWC implicit GEMM: tile 16x16 px, N=64, bf16 MFMA ----------------
// B-fragments double-buffered across taps (kills tap-serialized L2 latency).
__global__ __launch_bounds__(256, 2) void conv_nhwc_kernel(
    const unsigned short* __restrict__ A0, int c0stride,
    const unsigned short* __restrict__ A1, int nck0,
    const unsigned short* __restrict__ Wp,
    unsigned short* __restrict__ sl, int nchunks,
    const unsigned short* __restrict__ zp){
  int mt = blockIdx.x;
  int b = mt / 36; int r = mt - b * 36;
  int h0 = (r / 6) * 16, w0 = (r % 6) * 16;
  int KS = gridDim.y, ks = blockIdx.y;
  int c0 = (nchunks * ks) / KS, c1 = (nchunks * (ks + 1)) / KS;
  int tid = threadIdx.x, lane = tid & 63, wv = tid >> 6;
  int ln = lane & 15, kg = lane >> 4;
  __shared__ char halo[2][20736];   // 324 px * 64B, quad-XOR swizzled

  int pixb0[6], pixb1[6]; bool val[6];
  #pragma unroll
  for (int rr = 0; rr < 6; rr++){
    int i = tid + rr * 256;
    int p = i >> 2, q_lds = i & 3;
    int logq = q_lds ^ (p & 3);
    int hh = p / 18, ww = p - hh * 18;
    int h = h0 - 1 + hh, w = w0 - 1 + ww;
    bool v = (i < 1296) && ((unsigned)h < 96u) && ((unsigned)w < 96u);
    val[rr] = v;
    int pix = (b * 96 + h) * 96 + w;
    pixb0[rr] = v ? (pix * c0stride * 2 + logq * 16) : 0;
    pixb1[rr] = v ? (pix * 128 + logq * 16) : 0;
  }
  const char* a0B = (const char*)A0;
  const char* a1B = (const char*)A1;
  const char* zpB = (const char*)zp;

  auto stage = [&](int buf, int ck){
    bool inA0 = (ck < nck0);
    int chb0 = ck * 64, chb1 = (ck - nck0) * 64;
    char* ldsB = &halo[buf][0];
    #pragma unroll
    for (int rr = 0; rr < 6; rr++){
      int i = tid + rr * 256;
      if (i < 1296){
        const char* src = zpB;
        if (val[rr]) src = inA0 ? (a0B + pixb0[rr] + chb0) : (a1B + pixb1[rr] + chb1);
        gload16(src, ldsB + i * 16);
      }
    }
  };

  f32x4 acc[4][4];
  #pragma unroll
  for (int i = 0; i < 4; i++)
    #pragma unroll
    for (int j = 0; j < 4; j++) acc[i][j] = (f32x4)(0.f);

  stage(0, c0);
  __syncthreads();

  for (int ck = c0; ck < c1; ck++){
    int cur = (ck - c0) & 1;
    const unsigned short* wb = Wp + (size_t)ck * 18432 + ln * 32 + kg * 8;
    s16x8 bnx[4];
    #pragma unroll
    for (int nf = 0; nf < 4; nf++) bnx[nf] = *(const s16x8*)(wb + nf * 512);
    if (ck + 1 < c1) stage(cur ^ 1, ck + 1);
    const char* hb = &halo[cur][0];
    #pragma unroll
    for (int tap = 0; tap < 9; tap++){
      s16x8 bcur[4];
      #pragma unroll
      for (int nf = 0; nf < 4; nf++) bcur[nf] = bnx[nf];
      if (tap < 8){
        #pragma unroll
        for (int nf = 0; nf < 4; nf++)
          bnx[nf] = *(const s16x8*)(wb + (tap + 1) * 2048 + nf * 512);
      }
      int dy = tap / 3, dx = tap - dy * 3;
      #pragma unroll
      for (int mf = 0; mf < 4; mf++){
        int p = (wv * 4 + mf + dy) * 18 + (ln + dx);
        int aoff = p * 64 + ((kg ^ (p & 3)) << 4);
        s16x8 a = *(const s16x8*)(hb + aoff);
        #pragma unroll
        for (int nf = 0; nf < 4; nf++)
          acc[mf][nf] = __builtin_amdgcn_mfma_f32_16x16x32_bf16(a, bcur[nf], acc[mf][nf], 0, 0, 0);
      }
    }
    __syncthreads();
  }

  unsigned short* base = sl + ((size_t)(ks * 72 + mt)) * 16384;
  #pragma unroll
  for (int mf = 0; mf < 4; mf++)
    #pragma unroll
    for (int nf = 0; nf < 4; nf++){
      int o = nf * 16 + ln;
      #pragma unroll
      for (int rr = 0; rr < 4; rr++){
        int m = wv * 64 + mf * 16 + kg * 4 + rr;
        base[m * 64 + o] = f2bf(acc[mf][nf][rr]);
      }
    }
}

// ---------------- K-split reduce + BN (+ReLU) -> NHWC bf16 ----------------
__global__ __launch_bounds__(256) void bn_reduce_kernel(const unsigned short* __restrict__ sl,
    int KS, const float* __restrict__ g, const float* __restrict__ bb,
    const float* __restrict__ mm, const float* __restrict__ vv, int relu,
    unsigned short* __restrict__ out){
  int idx = blockIdx.x * 256 + threadIdx.x;
  int mt = idx >> 14, e = idx & 16383;
  int m = e >> 6, o = e & 63;
  float s = 0.f;
  for (int ks = 0; ks < KS; ks++) s += bf2f(sl[((size_t)(ks * 72 + mt)) * 16384 + e]);
  float sc = g[o] * rsqrtf(vv[o] + 1e-5f);
  float valf = (s - mm[o]) * sc + bb[o];
  if (relu) valf = fmaxf(valf, 0.f);
  int b = mt / 36; int r = mt - b * 36;
  int h = (r / 6) * 16 + (m >> 4), w = (r % 6) * 16 + (m & 15);
  out[(((size_t)b * 96 + h) * 96 + w) * 64 + o] = f2bf(valf);
}

// ---------------- K-split reduce + BN + fused cls2 (1x1 64->19) -> t19 f32 ----------------
__global__ __launch_bounds__(256) void bn_reduce_cls_kernel(const unsigned short* __restrict__ sl,
    int KS, const float* __restrict__ g, const float* __restrict__ bb,
    const float* __restrict__ mm, const float* __restrict__ vv,
    const float* __restrict__ w2, float* __restrict__ t19){
  __shared__ float yl[4][64];
  __shared__ float w2L[19 * 64];
  int tid = threadIdx.x;
  for (int i = tid; i < 1216; i += 256) w2L[i] = w2[i];
  int idx = blockIdx.x * 256 + tid;
  int mt = idx >> 14, e = idx & 16383;
  int o = e & 63;
  float s = 0.f;
  for (int ks = 0; ks < KS; ks++) s += bf2f(sl[((size_t)(ks * 72 + mt)) * 16384 + e]);
  float sc = g[o] * rsqrtf(vv[o] + 1e-5f);
  float valf = (s - mm[o]) * sc + bb[o];
  yl[tid >> 6][o] = valf;
  __syncthreads();
  if (tid < 76){
    int mq = tid / 19, j = tid - mq * 19;
    float a = 0.f;
    #pragma unroll 8
    for (int c = 0; c < 64; c++) a += w2L[j * 64 + c] * yl[mq][c];
    int m = ((blockIdx.x & 63) << 2) + mq;
    int b = mt / 36; int r = mt - b * 36;
    int h = (r / 6) * 16 + (m >> 4), w = (r % 6) * 16 + (m & 15);
    t19[((size_t)(b * 19 + j)) * HW + h * 96 + w] = a;
  }
}

// ---------------- CCA: q,k,v projections -> pixel-major q[px][8], k[px][8], v[px][64] ----------------
__global__ __launch_bounds__(128) void cca_proj_kernel(const unsigned short* __restrict__ xin,
    const float* __restrict__ wq, const float* __restrict__ wk, const float* __restrict__ wv,
    float* __restrict__ q, float* __restrict__ k, float* __restrict__ v){
  __shared__ float wqL[512], wkL[512], wvL[4096];
  int tid = threadIdx.x;
  for (int i = tid; i < 512; i += 128){ wqL[i] = wq[i]; wkL[i] = wk[i]; }
  for (int i = tid; i < 4096; i += 128) wvL[i] = wv[i];
  __syncthreads();
  int gp = blockIdx.x * 128 + tid;
  unsigned short xv16[64];
  #pragma unroll
  for (int t = 0; t < 8; t++)
    *(s16x8*)(&xv16[t * 8]) = *(const s16x8*)(xin + (size_t)gp * 64 + t * 8);
  float qa[8], ka[8], va[64];
  #pragma unroll
  for (int d = 0; d < 8; d++){ qa[d] = 0.f; ka[d] = 0.f; }
  #pragma unroll
  for (int d = 0; d < 64; d++) va[d] = 0.f;
  #pragma unroll 4
  for (int c = 0; c < 64; c++){
    float xv = bf2f(xv16[c]);
    #pragma unroll
    for (int d = 0; d < 8; d++){ qa[d] += wqL[d * 64 + c] * xv; ka[d] += wkL[d * 64 + c] * xv; }
    #pragma unroll
    for (int d = 0; d < 64; d++) va[d] += wvL[d * 64 + c] * xv;
  }
  #pragma unroll
  for (int d = 0; d < 8; d++){ q[(size_t)gp * 8 + d] = qa[d]; k[(size_t)gp * 8 + d] = ka[d]; }
  #pragma unroll
  for (int d = 0; d < 64; d++) v[(size_t)gp * 64 + d] = va[d];
}

// ---------------- CCA: column energies eH -> ebuf[b][h][w][kp] (diag masked) ----------------
__global__ __launch_bounds__(256, 2) void cca_colE_kernel(const float* __restrict__ qT,
    const float* __restrict__ kT, float* __restrict__ ebuf){
  int blk = blockIdx.x; int b = blk / 96, w = blk - b * 96;
  __shared__ float qcL[96 * 12], kcL[96 * 12];
  int tid = threadIdx.x;
  for (int i = tid; i < 768; i += 256){
    int hp = i >> 3, d = i & 7;
    size_t gidx = ((size_t)(b * HW) + hp * 96 + w) * 8 + d;
    qcL[hp * 12 + d] = qT[gidx];
    kcL[hp * 12 + d] = kT[gidx];
  }
  __syncthreads();
  int hb = tid & 15, kb2 = tid >> 4;
  int h0 = hb * 6, kp0 = kb2 * 6;
  f32x4 q0[6], q1[6], k0[6], k1[6];
  #pragma unroll
  for (int i = 0; i < 6; i++){
    q0[i] = *(const f32x4*)&qcL[(h0 + i) * 12];
    q1[i] = *(const f32x4*)&qcL[(h0 + i) * 12 + 4];
    k0[i] = *(const f32x4*)&kcL[(kp0 + i) * 12];
    k1[i] = *(const f32x4*)&kcL[(kp0 + i) * 12 + 4];
  }
  #pragma unroll
  for (int i = 0; i < 6; i++){
    size_t rbase = (((size_t)b * 96 + (h0 + i)) * 96 + w) * 96;
    #pragma unroll
    for (int j = 0; j < 6; j++){
      float e = 0.f;
      #pragma unroll
      for (int d = 0; d < 4; d++) e += q0[i][d] * k0[j][d] + q1[i][d] * k1[j][d];
      ebuf[rbase + kp0 + j] = (kp0 + j == h0 + i) ? -1e30f : e;
    }
  }
}

// ---------------- CCA: row kernel — eW, joint softmax, oW partial ----------------
__global__ __launch_bounds__(256, 2) void cca_rowSM_kernel(const float* __restrict__ qT,
    const float* __restrict__ kT, const float* __restrict__ vT,
    const unsigned short* __restrict__ xin, const float* __restrict__ gamma,
    float* __restrict__ ebuf, unsigned short* __restrict__ xout){
  int blk = blockIdx.x; int b = blk / 96, h = blk - b * 96;
  __shared__ float qrL[96 * 12], krL[96 * 12];
  __shared__ float vL[96 * 68];
  __shared__ float ewT[96 * 102];   // [kp][w]
  int tid = threadIdx.x;
  size_t rowb = (size_t)(b * HW) + h * 96;   // pixel index of row start
  for (int i = tid; i < 768; i += 256){
    int wp = i >> 3, d = i & 7;
    qrL[wp * 12 + d] = qT[(rowb + wp) * 8 + d];
    krL[wp * 12 + d] = kT[(rowb + wp) * 8 + d];
  }
  for (int i = tid; i < 6144; i += 256){
    int wp = i >> 6, d = i & 63;
    vL[wp * 68 + d] = vT[(rowb + wp) * 64 + d];
  }
  __syncthreads();
  {  // energies eW[w][kp] = sum_d q[w][d] k[kp][d]  -> ewT[kp][w]
    int wb_ = tid & 15, kb_ = tid >> 4;
    int w0 = wb_ * 6, kp0 = kb_ * 6;
    f32x4 q0[6], q1[6], k0[6], k1[6];
    #pragma unroll
    for (int i = 0; i < 6; i++){
      q0[i] = *(const f32x4*)&qrL[(w0 + i) * 12];
      q1[i] = *(const f32x4*)&qrL[(w0 + i) * 12 + 4];
      k0[i] = *(const f32x4*)&krL[(kp0 + i) * 12];
      k1[i] = *(const f32x4*)&krL[(kp0 + i) * 12 + 4];
    }
    #pragma unroll
    for (int j = 0; j < 6; j++)
      #pragma unroll
      for (int i = 0; i < 6; i++){
        float e = 0.f;
        #pragma unroll
        for (int d = 0; d < 4; d++) e += q0[i][d] * k0[j][d] + q1[i][d] * k1[j][d];
        ewT[(kp0 + j) * 102 + (w0 + i)] = e;
      }
  }
  __syncthreads();
  int lane = tid & 63, wvid = tid >> 6;
  for (int w = wvid; w < 96; w += 4){
    float* eb2 = ebuf + (((size_t)b * 96 + h) * 96 + w) * 96;
    float x0 = eb2[lane];
    float x1 = (lane < 32) ? eb2[64 + lane] : ewT[(lane - 32) * 102 + w];
    float x2 = ewT[(lane + 32) * 102 + w];
    float mx = fmaxf(x0, fmaxf(x1, x2));
    #pragma unroll
    for (int s = 32; s; s >>= 1) mx = fmaxf(mx, __shfl_xor(mx, s));
    float e0 = __expf(x0 - mx), e1 = __expf(x1 - mx), e2 = __expf(x2 - mx);
    float sm = e0 + e1 + e2;
    #pragma unroll
    for (int s = 32; s; s >>= 1) sm += __shfl_xor(sm, s);
    float inv = 1.f / sm;
    eb2[lane] = e0 * inv;
    if (lane < 32) eb2[64 + lane] = e1 * inv; else ewT[(lane - 32) * 102 + w] = e1 * inv;
    ewT[(lane + 32) * 102 + w] = e2 * inv;
  }
  __syncthreads();
  float gm = gamma[0];
  int db_ = tid & 15, wb2 = tid >> 4;
  int d0 = db_ * 4, w0 = wb2 * 6;
  f32x4 acc2[6];
  #pragma unroll
  for (int c = 0; c < 6; c++) acc2[c] = (f32x4)(0.f);
  for (int kp = 0; kp < 96; kp++){
    f32x4 vv = *(const f32x4*)&vL[kp * 68 + d0];
    float2 a01 = *(const float2*)&ewT[kp * 102 + w0];
    float2 a23 = *(const float2*)&ewT[kp * 102 + w0 + 2];
    float2 a45 = *(const float2*)&ewT[kp * 102 + w0 + 4];
    acc2[0] += vv * a01.x; acc2[1] += vv * a01.y;
    acc2[2] += vv * a23.x; acc2[3] += vv * a23.y;
    acc2[4] += vv * a45.x; acc2[5] += vv * a45.y;
  }
  #pragma unroll
  for (int c = 0; c < 6; c++){
    size_t pix = rowb + (w0 + c);
    ushort4 xr = *(const ushort4*)&xin[pix * 64 + d0];
    ushort4 ov;
    ov.x = f2bf(bf2f(xr.x) + gm * acc2[c][0]);
    ov.y = f2bf(bf2f(xr.y) + gm * acc2[c][1]);
    ov.z = f2bf(bf2f(xr.z) + gm * acc2[c][2]);
    ov.w = f2bf(bf2f(xr.w) + gm * acc2[c][3]);
    *(ushort4*)&xout[pix * 64 + d0] = ov;
  }
}

// ---------------- CCA: column kernel — oH + final accumulate ----------------
__global__ __launch_bounds__(256, 2) void cca_colO_kernel(const float* __restrict__ vT,
    const float* __restrict__ gamma, const float* __restrict__ ebuf,
    const unsigned short* __restrict__ xpart, unsigned short* __restrict__ xout){
  int blk = blockIdx.x; int b = blk / 96, w = blk - b * 96;
  __shared__ float vL[96 * 68];    // [kp(H)][d]
  __shared__ float aT[96 * 102];   // [kp][hh]
  int tid = threadIdx.x;
  for (int i = tid; i < 6144; i += 256){
    int kp = i >> 6, d = i & 63;
    vL[kp * 68 + d] = vT[((size_t)(b * HW) + kp * 96 + w) * 64 + d];
  }
  for (int i = tid; i < 9216; i += 256){
    int hh = i / 96, kp = i - hh * 96;
    aT[kp * 102 + hh] = ebuf[(((size_t)b * 96 + hh) * 96 + w) * 96 + kp];
  }
  __syncthreads();
  float gm = gamma[0];
  int db_ = tid & 15, hb2 = tid >> 4;
  int d0 = db_ * 4, h0 = hb2 * 6;
  f32x4 acc2[6];
  #pragma unroll
  for (int c = 0; c < 6; c++) acc2[c] = (f32x4)(0.f);
  for (int kp = 0; kp < 96; kp++){
    f32x4 vv = *(const f32x4*)&vL[kp * 68 + d0];
    float2 a01 = *(const float2*)&aT[kp * 102 + h0];
    float2 a23 = *(const float2*)&aT[kp * 102 + h0 + 2];
    float2 a45 = *(const float2*)&aT[kp * 102 + h0 + 4];
    acc2[0] += vv * a01.x; acc2[1] += vv * a01.y;
    acc2[2] += vv * a23.x; acc2[3] += vv * a23.y;
    acc2[4] += vv * a45.x; acc2[5] += vv * a45.y;
  }
  #pragma unroll
  for (int c = 0; c < 6; c++){
    size_t pix = (size_t)(b * HW) + (h0 + c) * 96 + w;
    ushort4 xr = *(const ushort4*)&xpart[pix * 64 + d0];
    ushort4 ov;
    ov.x = f2bf(bf2f(xr.x) + gm * acc2[c][0]);
    ov.y = f2bf(bf2f(xr.y) + gm * acc2[c][1]);
    ov.z = f2bf(bf2f(xr.z) + gm * acc2[c][2]);
    ov.w = f2bf(bf2f(xr.w) + gm * acc2[c][3]);
    *(ushort4*)&xout[pix * 64 + d0] = ov;
  }
}

// ---------------- bilinear x8 upsample (align_corners) of 19ch ----------------
__global__ void upsample_kernel(const float* __restrict__ t19, float* __restrict__ out){
  int gid = blockIdx.x * 256 + threadIdx.x;
  int xq = gid % 192; int t = gid / 192;
  int yy = t % 768; t /= 768;
  int o = t % 19; int b = t / 19;
  const float R = 95.0f / 767.0f;
  float ry = yy * R;
  int iy = (int)ry;
  float fy = ry - (float)iy;
  int iy1 = min(iy + 1, 95);
  const float* base = t19 + ((size_t)b * 19 + o) * HW;
  float4 res;
  float* rp = (float*)&res;
  #pragma unroll
  for (int j = 0; j < 4; j++){
    int xx = xq * 4 + j;
    float rx = xx * R;
    int ix = (int)rx; float fx = rx - (float)ix; int ix1 = min(ix + 1, 95);
    float v00 = base[iy * 96 + ix],  v01 = base[iy * 96 + ix1];
    float v10 = base[iy1 * 96 + ix], v11 = base[iy1 * 96 + ix1];
    rp[j] = (1.f - fy) * ((1.f - fx) * v00 + fx * v01) + fy * ((1.f - fx) * v10 + fx * v11);
  }
  *(float4*)(out + (((size_t)b * 19 + o) * 768 + yy) * 768 + xq * 4) = res;
}

// ---------------- host-side orchestration ----------------
extern "C" void kernel_launch(void* const* d_in, const int* in_sizes, int n_in,
                              void* d_out, int out_size, void* d_ws, size_t ws_size,
                              hipStream_t stream){
  const float* x       = (const float*)d_in[0];
  const float* w_in    = (const float*)d_in[1];
  const float* bn_in_g = (const float*)d_in[2];
  const float* bn_in_b = (const float*)d_in[3];
  const float* bn_in_m = (const float*)d_in[4];
  const float* bn_in_v = (const float*)d_in[5];
  const float* wq      = (const float*)d_in[6];
  const float* wk      = (const float*)d_in[7];
  const float* wv      = (const float*)d_in[8];
  const float* gamma   = (const float*)d_in[9];
  const float* w_out   = (const float*)d_in[10];
  const float* bn_o_g  = (const float*)d_in[11];
  const float* bn_o_b  = (const float*)d_in[12];
  const float* bn_o_m  = (const float*)d_in[13];
  const float* bn_o_v  = (const float*)d_in[14];
  const float* w_cls1  = (const float*)d_in[15];
  const float* bn_c_g  = (const float*)d_in[16];
  const float* bn_c_b  = (const float*)d_in[17];
  const float* bn_c_m  = (const float*)d_in[18];
  const float* bn_c_v  = (const float*)d_in[19];
  const float* w_cls2  = (const float*)d_in[20];
  float* out = (float*)d_out;

  char* ws = (char*)d_ws;
  size_t off = 0;
  auto alloc = [&](size_t bytes) -> void* {
    void* p = ws + off; off += (bytes + 255) & ~(size_t)255; return p;
  };
  const size_t NHWCb = (size_t)2 * HW * 64 * 2;                 // 2.36 MB
  unsigned short* xT   = (unsigned short*)alloc((size_t)2 * HW * 2048 * 2);  // 75.5 MB
  unsigned short* sl   = (unsigned short*)alloc((size_t)8 * 72 * 16384 * 2); // 18.9 MB (also ebuf)
  float* ebuf = (float*)sl;                                     // CCA-phase reuse [b][h][w][96]
  unsigned short* xattA = (unsigned short*)alloc(NHWCb);
  unsigned short* xattB = (unsigned short*)alloc(NHWCb);
  unsigned short* Ptmp  = (unsigned short*)alloc(NHWCb);
  unsigned short* attT  = (unsigned short*)alloc(NHWCb);
  unsigned short* midT  = (unsigned short*)alloc(NHWCb);
  float* qb    = (float*)alloc((size_t)2 * HW * 8 * 4);
  float* kb    = (float*)alloc((size_t)2 * HW * 8 * 4);
  float* vb    = (float*)alloc((size_t)2 * HW * 64 * 4);
  float* t19   = (float*)alloc((size_t)2 * 19 * HW * 4);
  unsigned short* WpIn  = (unsigned short*)alloc((size_t)64 * 2048 * 9 * 2);
  unsigned short* WpOut = (unsigned short*)alloc((size_t)64 * 64 * 9 * 2);
  unsigned short* WpCls = (unsigned short*)alloc((size_t)64 * 2112 * 9 * 2);
  unsigned short* zp    = (unsigned short*)alloc(256);
  (void)ws_size; (void)in_sizes; (void)n_in; (void)out_size;

  hipMemsetAsync(zp, 0, 256, stream);
  transp_kernel<<<2304, 256, 0, stream>>>(x, xT);
  packw_kernel<<<1024, 256, 0, stream>>>(w_in,   WpIn,  2048);
  packw_kernel<<<64,   256, 0, stream>>>(w_out,  WpOut, 64);
  packw_kernel<<<1024, 256, 0, stream>>>(w_cls1, WpCls, 2112);

  // conv_in (2048 -> 64) + BN + ReLU -> xattA (NHWC bf16)
  conv_nhwc_kernel<<<dim3(72, 8), 256, 0, stream>>>(xT, 2048, nullptr, 64, WpIn, sl, 64, zp);
  bn_reduce_kernel<<<4608, 256, 0, stream>>>(sl, 8, bn_in_g, bn_in_b, bn_in_m, bn_in_v, 1, xattA);

  // CCA pass 1: xattA -> xattB
  cca_proj_kernel<<<144, 128, 0, stream>>>(xattA, wq, wk, wv, qb, kb, vb);
  cca_colE_kernel<<<192, 256, 0, stream>>>(qb, kb, ebuf);
  cca_rowSM_kernel<<<192, 256, 0, stream>>>(qb, kb, vb, xattA, gamma, ebuf, Ptmp);
  cca_colO_kernel<<<192, 256, 0, stream>>>(vb, gamma, ebuf, Ptmp, xattB);
  // CCA pass 2: xattB -> attT
  cca_proj_kernel<<<144, 128, 0, stream>>>(xattB, wq, wk, wv, qb, kb, vb);
  cca_colE_kernel<<<192, 256, 0, stream>>>(qb, kb, ebuf);
  cca_rowSM_kernel<<<192, 256, 0, stream>>>(qb, kb, vb, xattB, gamma, ebuf, Ptmp);
  cca_colO_kernel<<<192, 256, 0, stream>>>(vb, gamma, ebuf, Ptmp, attT);

  // conv_out (64 -> 64) + BN + ReLU -> midT
  conv_nhwc_kernel<<<dim3(72, 2), 256, 0, stream>>>(attT, 64, nullptr, 2, WpOut, sl, 2, zp);
  bn_reduce_kernel<<<4608, 256, 0, stream>>>(sl, 2, bn_o_g, bn_o_b, bn_o_m, bn_o_v, 1, midT);

  // cls1 conv on concat([x, mid]) (2112 -> 64) + BN + fused cls2 -> t19
  conv_nhwc_kernel<<<dim3(72, 8), 256, 0, stream>>>(xT, 2048, midT, 64, WpCls, sl, 66, zp);
  bn_reduce_cls_kernel<<<4608, 256, 0, stream>>>(sl, 8, bn_c_g, bn_c_b, bn_c_m, bn_c_v, w_cls2, t19);

  // bilinear x8 upsample of 19ch (commuted with 1x1 conv)
  upsample_kernel<<<21888, 256, 0, stream>>>(t19, out);
}

// Round 5
// 480.687 us; speedup vs baseline: 2.0457x; 1.0882x over previous
//
#include <hip/hip_runtime.h>
#include <stdint.h>

#define HW 9216   // 96*96

typedef float f32x4 __attribute__((ext_vector_type(4)));
typedef short s16x8 __attribute__((ext_vector_type(8)));

#define PIN() asm volatile("" ::: "memory")
#define WAITV12() asm volatile("s_waitcnt vmcnt(12)" ::: "memory")

__device__ __forceinline__ unsigned short f2bf(float f){
  union { float fv; uint32_t u; } x; x.fv = f;
  uint32_t u = x.u;
  u += 0x7fffu + ((u >> 16) & 1u);   // RNE
  return (unsigned short)(u >> 16);
}
__device__ __forceinline__ float bf2f(unsigned short s){
  union { uint32_t u; float fv; } x; x.u = ((uint32_t)s) << 16;
  return x.fv;
}

__device__ __forceinline__ void gload16(const void* g, void* l){
  __builtin_amdgcn_global_load_lds(
    (const __attribute__((address_space(1))) unsigned int*)g,
    (__attribute__((address_space(3))) unsigned int*)l, 16, 0, 0);
}

// ---------------- NCHW f32 -> NHWC bf16 transpose (x only) ----------------
__global__ __launch_bounds__(256) void transp_kernel(const float* __restrict__ x,
    unsigned short* __restrict__ xT){
  __shared__ unsigned short tl[256 * 66];   // [cc][px] pad 66
  int blk = blockIdx.x;
  int b = blk / 1152; int r = blk - b * 1152;
  int cchunk = r / 144, pxt = r - cchunk * 144;
  int c0 = cchunk * 256, px0 = pxt * 64;
  int tid = threadIdx.x;
  for (int e = tid; e < 4096; e += 256){
    int cc = e >> 4, pq = e & 15;
    float4 v4 = *(const float4*)(x + ((size_t)(b * 2048 + c0 + cc)) * HW + px0 + pq * 4);
    const float* vp = (const float*)&v4;
    #pragma unroll
    for (int j = 0; j < 4; j++) tl[cc * 66 + pq * 4 + j] = f2bf(vp[j]);
  }
  __syncthreads();
  for (int j = tid; j < 2048; j += 256){
    int px = j >> 5, oct = j & 31;
    s16x8 pk;
    #pragma unroll
    for (int t = 0; t < 8; t++) pk[t] = (short)tl[(oct * 8 + t) * 66 + px];
    *(s16x8*)(xT + ((size_t)(b * 9216 + px0 + px)) * 2048 + c0 + oct * 8) = pk;
  }
}

// ---------------- weight pack: Wp[((ck*9 + tap)*64 + o)*32 + c] ----------------
__global__ void packw_kernel(const float* __restrict__ w, unsigned short* __restrict__ Wp, int Cin){
  int total = 64 * Cin * 9;
  for (int i = blockIdx.x * blockDim.x + threadIdx.x; i < total; i += gridDim.x * blockDim.x){
    int c = i & 31; int r = i >> 5; int o = r & 63; int r2 = r >> 6;
    int tap = r2 % 9; int ck = r2 / 9;
    Wp[i] = f2bf(w[((size_t)o * Cin + ck * 32 + c) * 9 + tap]);
  }
}

// -------- per-tap body: 4 ds_read + 16 MFMA + rolling B prefetch (slot T%3, 3 taps ahead) --------
template<int T>
__device__ __forceinline__ void tapbody(const char* hb, s16x8 (&bs)[4], f32x4 (&acc)[4][4],
    const unsigned short* wbase, int gmax, int g0, int wv, int ln, int kg){
  constexpr int dy = T / 3, dx = T - dy * 3;
  #pragma unroll
  for (int mf = 0; mf < 4; mf++){
    int p = (wv * 4 + mf + dy) * 18 + (ln + dx);
    int aoff = p * 64 + ((kg ^ (p & 3)) << 4);
    s16x8 a = *(const s16x8*)(hb + aoff);
    #pragma unroll
    for (int nf = 0; nf < 4; nf++)
      acc[mf][nf] = __builtin_amdgcn_mfma_f32_16x16x32_bf16(a, bs[nf], acc[mf][nf], 0, 0, 0);
  }
  constexpr int dck = (T + 3) / 9, dt = (T + 3) % 9;   // prefetch target (may be next chunk)
  if (g0 + T + 3 < gmax){
    const unsigned short* wb2 = wbase + dck * 18432 + dt * 2048;
    #pragma unroll
    for (int nf = 0; nf < 4; nf++) bs[nf] = *(const s16x8*)(wb2 + nf * 512);
  }
}

// ---------------- conv3x3 NHWC implicit GEMM: tile 16x16 px, N=64, bf16 MFMA ----------------
// 2-buffer LDS halo + counted-vmcnt barrier (no vmcnt(0) drain), 3-deep rolling B prefetch.
__global__ __launch_bounds__(256, 2) void conv_nhwc_kernel(
    const unsigned short* __restrict__ A0, int c0stride,
    const unsigned short* __restrict__ A1, int nck0,
    const unsigned short* __restrict__ Wp,
    unsigned short* __restrict__ sl, int nchunks,
    const unsigned short* __restrict__ zp){
  int mt = blockIdx.x;
  int b = mt / 36; int r = mt - b * 36;
  int h0 = (r / 6) * 16, w0 = (r % 6) * 16;
  int KS = gridDim.y, ks = blockIdx.y;
  int c0 = (nchunks * ks) / KS, c1 = (nchunks * (ks + 1)) / KS;
  int tid = threadIdx.x, lane = tid & 63, wv = tid >> 6;
  int ln = lane & 15, kg = lane >> 4;
  __shared__ char halo[2][24576];   // 324 px * 64B (+pad), quad-XOR swizzled

  int pixb0[6], pixb1[6]; bool val[6];
  #pragma unroll
  for (int rr = 0; rr < 6; rr++){
    int i = tid + rr * 256;
    int p = i >> 2, q_lds = i & 3;
    int logq = q_lds ^ (p & 3);
    int hh = p / 18, ww = p - hh * 18;
    int h = h0 - 1 + hh, w = w0 - 1 + ww;
    bool v = (i < 1296) && ((unsigned)h < 96u) && ((unsigned)w < 96u);
    val[rr] = v;
    int pix = (b * 96 + h) * 96 + w;
    pixb0[rr] = v ? (pix * c0stride * 2 + logq * 16) : 0;
    pixb1[rr] = v ? (pix * 128 + logq * 16) : 0;
  }
  const char* a0B = (const char*)A0;
  const char* a1B = (const char*)A1;
  const char* zpB = (const char*)zp;

  // uniform 6 gload_lds per thread (items >=1296 land in buffer pad, src = zeros)
  auto stage = [&](char* ldsB, int ck){
    bool inA0 = (ck < nck0);
    int chb0 = ck * 64, chb1 = (ck - nck0) * 64;
    #pragma unroll
    for (int rr = 0; rr < 6; rr++){
      const char* src = zpB;
      if (val[rr]) src = inA0 ? (a0B + pixb0[rr] + chb0) : (a1B + pixb1[rr] + chb1);
      gload16(src, ldsB + (tid + rr * 256) * 16);
    }
  };

  f32x4 acc[4][4];
  #pragma unroll
  for (int i = 0; i < 4; i++)
    #pragma unroll
    for (int j = 0; j < 4; j++) acc[i][j] = (f32x4)(0.f);

  s16x8 bs0[4], bs1[4], bs2[4];
  int gmax = (c1 - c0) * 9;

  // prologue: stage chunk c0, prime B slots (taps 0..2), counted wait
  stage(&halo[0][0], c0);
  PIN();
  {
    const unsigned short* w0b = Wp + (size_t)c0 * 18432 + ln * 32 + kg * 8;
    #pragma unroll
    for (int nf = 0; nf < 4; nf++){
      bs0[nf] = *(const s16x8*)(w0b + 0 * 2048 + nf * 512);
      bs1[nf] = *(const s16x8*)(w0b + 1 * 2048 + nf * 512);
      bs2[nf] = *(const s16x8*)(w0b + 2 * 2048 + nf * 512);
    }
  }
  WAITV12();
  __builtin_amdgcn_s_barrier();

  for (int ck = c0; ck < c1; ck++){
    int cur = (ck - c0) & 1;
    if (ck + 1 < c1){ stage(&halo[cur ^ 1][0], ck + 1); PIN(); }
    const unsigned short* wbase = Wp + (size_t)ck * 18432 + ln * 32 + kg * 8;
    const char* hb = &halo[cur][0];
    int g0 = (ck - c0) * 9;
    tapbody<0>(hb, bs0, acc, wbase, gmax, g0, wv, ln, kg);
    tapbody<1>(hb, bs1, acc, wbase, gmax, g0, wv, ln, kg);
    tapbody<2>(hb, bs2, acc, wbase, gmax, g0, wv, ln, kg);
    tapbody<3>(hb, bs0, acc, wbase, gmax, g0, wv, ln, kg);
    tapbody<4>(hb, bs1, acc, wbase, gmax, g0, wv, ln, kg);
    tapbody<5>(hb, bs2, acc, wbase, gmax, g0, wv, ln, kg);
    tapbody<6>(hb, bs0, acc, wbase, gmax, g0, wv, ln, kg);
    tapbody<7>(hb, bs1, acc, wbase, gmax, g0, wv, ln, kg);
    tapbody<8>(hb, bs2, acc, wbase, gmax, g0, wv, ln, kg);
    if (ck + 1 < c1){
      WAITV12();                       // retires the 6 stage loads, keeps B prefetches in flight
      __builtin_amdgcn_s_barrier();
    }
  }

  unsigned short* base = sl + ((size_t)(ks * 72 + mt)) * 16384;
  #pragma unroll
  for (int mf = 0; mf < 4; mf++)
    #pragma unroll
    for (int nf = 0; nf < 4; nf++){
      int o = nf * 16 + ln;
      #pragma unroll
      for (int rr = 0; rr < 4; rr++){
        int m = wv * 64 + mf * 16 + kg * 4 + rr;
        base[m * 64 + o] = f2bf(acc[mf][nf][rr]);
      }
    }
}

// ---------------- K-split reduce + BN (+ReLU) -> NHWC bf16 ----------------
__global__ __launch_bounds__(256) void bn_reduce_kernel(const unsigned short* __restrict__ sl,
    int KS, const float* __restrict__ g, const float* __restrict__ bb,
    const float* __restrict__ mm, const float* __restrict__ vv, int relu,
    unsigned short* __restrict__ out){
  int idx = blockIdx.x * 256 + threadIdx.x;
  int mt = idx >> 14, e = idx & 16383;
  int m = e >> 6, o = e & 63;
  float s = 0.f;
  for (int ks = 0; ks < KS; ks++) s += bf2f(sl[((size_t)(ks * 72 + mt)) * 16384 + e]);
  float sc = g[o] * rsqrtf(vv[o] + 1e-5f);
  float valf = (s - mm[o]) * sc + bb[o];
  if (relu) valf = fmaxf(valf, 0.f);
  int b = mt / 36; int r = mt - b * 36;
  int h = (r / 6) * 16 + (m >> 4), w = (r % 6) * 16 + (m & 15);
  out[(((size_t)b * 96 + h) * 96 + w) * 64 + o] = f2bf(valf);
}

// ---------------- K-split reduce + BN + fused cls2 (1x1 64->19) -> t19 f32 ----------------
__global__ __launch_bounds__(256) void bn_reduce_cls_kernel(const unsigned short* __restrict__ sl,
    int KS, const float* __restrict__ g, const float* __restrict__ bb,
    const float* __restrict__ mm, const float* __restrict__ vv,
    const float* __restrict__ w2, float* __restrict__ t19){
  __shared__ float yl[4][64];
  __shared__ float w2L[19 * 64];
  int tid = threadIdx.x;
  for (int i = tid; i < 1216; i += 256) w2L[i] = w2[i];
  int idx = blockIdx.x * 256 + tid;
  int mt = idx >> 14, e = idx & 16383;
  int o = e & 63;
  float s = 0.f;
  for (int ks = 0; ks < KS; ks++) s += bf2f(sl[((size_t)(ks * 72 + mt)) * 16384 + e]);
  float sc = g[o] * rsqrtf(vv[o] + 1e-5f);
  float valf = (s - mm[o]) * sc + bb[o];
  yl[tid >> 6][o] = valf;
  __syncthreads();
  if (tid < 76){
    int mq = tid / 19, j = tid - mq * 19;
    float a = 0.f;
    #pragma unroll 8
    for (int c = 0; c < 64; c++) a += w2L[j * 64 + c] * yl[mq][c];
    int m = ((blockIdx.x & 63) << 2) + mq;
    int b = mt / 36; int r = mt - b * 36;
    int h = (r / 6) * 16 + (m >> 4), w = (r % 6) * 16 + (m & 15);
    t19[((size_t)(b * 19 + j)) * HW + h * 96 + w] = a;
  }
}

// ---------------- CCA: q,k,v projections -> pixel-major q[px][8], k[px][8], v[px][64] ----------------
__global__ __launch_bounds__(128) void cca_proj_kernel(const unsigned short* __restrict__ xin,
    const float* __restrict__ wq, const float* __restrict__ wk, const float* __restrict__ wv,
    float* __restrict__ q, float* __restrict__ k, float* __restrict__ v){
  __shared__ float wqL[512], wkL[512], wvL[4096];
  int tid = threadIdx.x;
  for (int i = tid; i < 512; i += 128){ wqL[i] = wq[i]; wkL[i] = wk[i]; }
  for (int i = tid; i < 4096; i += 128) wvL[i] = wv[i];
  __syncthreads();
  int gp = blockIdx.x * 128 + tid;
  unsigned short xv16[64];
  #pragma unroll
  for (int t = 0; t < 8; t++)
    *(s16x8*)(&xv16[t * 8]) = *(const s16x8*)(xin + (size_t)gp * 64 + t * 8);
  float qa[8], ka[8], va[64];
  #pragma unroll
  for (int d = 0; d < 8; d++){ qa[d] = 0.f; ka[d] = 0.f; }
  #pragma unroll
  for (int d = 0; d < 64; d++) va[d] = 0.f;
  #pragma unroll 4
  for (int c = 0; c < 64; c++){
    float xv = bf2f(xv16[c]);
    #pragma unroll
    for (int d = 0; d < 8; d++){ qa[d] += wqL[d * 64 + c] * xv; ka[d] += wkL[d * 64 + c] * xv; }
    #pragma unroll
    for (int d = 0; d < 64; d++) va[d] += wvL[d * 64 + c] * xv;
  }
  #pragma unroll
  for (int d = 0; d < 8; d++){ q[(size_t)gp * 8 + d] = qa[d]; k[(size_t)gp * 8 + d] = ka[d]; }
  #pragma unroll
  for (int d = 0; d < 64; d++) v[(size_t)gp * 64 + d] = va[d];
}

// ---------------- CCA: column energies eH -> ebuf[b][h][w][kp] (diag masked, f32) ----------------
__global__ __launch_bounds__(256, 2) void cca_colE_kernel(const float* __restrict__ qT,
    const float* __restrict__ kT, float* __restrict__ ebuf){
  int blk = blockIdx.x; int b = blk / 96, w = blk - b * 96;
  __shared__ float qcL[96 * 12], kcL[96 * 12];
  int tid = threadIdx.x;
  for (int i = tid; i < 768; i += 256){
    int hp = i >> 3, d = i & 7;
    size_t gidx = ((size_t)(b * HW) + hp * 96 + w) * 8 + d;
    qcL[hp * 12 + d] = qT[gidx];
    kcL[hp * 12 + d] = kT[gidx];
  }
  __syncthreads();
  int hb = tid & 15, kb2 = tid >> 4;
  int h0 = hb * 6, kp0 = kb2 * 6;
  f32x4 q0[6], q1[6], k0[6], k1[6];
  #pragma unroll
  for (int i = 0; i < 6; i++){
    q0[i] = *(const f32x4*)&qcL[(h0 + i) * 12];
    q1[i] = *(const f32x4*)&qcL[(h0 + i) * 12 + 4];
    k0[i] = *(const f32x4*)&kcL[(kp0 + i) * 12];
    k1[i] = *(const f32x4*)&kcL[(kp0 + i) * 12 + 4];
  }
  #pragma unroll
  for (int i = 0; i < 6; i++){
    size_t rbase = (((size_t)b * 96 + (h0 + i)) * 96 + w) * 96;
    #pragma unroll
    for (int j = 0; j < 6; j++){
      float e = 0.f;
      #pragma unroll
      for (int d = 0; d < 4; d++) e += q0[i][d] * k0[j][d] + q1[i][d] * k1[j][d];
      ebuf[rbase + kp0 + j] = (kp0 + j == h0 + i) ? -1e30f : e;
    }
  }
}

// ---------------- CCA: row kernel — eW, joint softmax (reg-prefetched), oW partial ----------------
__global__ __launch_bounds__(256, 1) void cca_rowSM_kernel(const float* __restrict__ qT,
    const float* __restrict__ kT, const float* __restrict__ vT,
    const unsigned short* __restrict__ xin, const float* __restrict__ gamma,
    float* __restrict__ ebuf, unsigned short* __restrict__ xout){
  int blk = blockIdx.x; int b = blk / 96, h = blk - b * 96;
  __shared__ float qrL[96 * 12], krL[96 * 12];
  __shared__ float ewT[96 * 102];          // f32 energies [kp][w]
  __shared__ unsigned short vL2[96 * 68];  // bf16 v [w-pos][d]
  __shared__ unsigned short aW[96 * 100];  // bf16 normalized attention [kp][w]
  int tid = threadIdx.x;
  int lane = tid & 63, wvid = tid >> 6;
  size_t rowb = (size_t)(b * HW) + h * 96;
  const float* ebase = ebuf + rowb * 96;   // [w][kp]

  // bulk-preload softmax eH operands (one latency exposure instead of 24)
  float pre0[24], pre1[24];
  #pragma unroll
  for (int t = 0; t < 24; t++){
    int w = wvid + t * 4;
    pre0[t] = ebase[(size_t)w * 96 + lane];
    pre1[t] = (lane < 32) ? ebase[(size_t)w * 96 + 64 + lane] : 0.f;
  }

  for (int i = tid; i < 768; i += 256){
    int wp = i >> 3, d = i & 7;
    qrL[wp * 12 + d] = qT[(rowb + wp) * 8 + d];
    krL[wp * 12 + d] = kT[(rowb + wp) * 8 + d];
  }
  for (int i = tid; i < 6144; i += 256){
    int wp = i >> 6, d = i & 63;
    vL2[wp * 68 + d] = f2bf(vT[(rowb + wp) * 64 + d]);
  }
  __syncthreads();
  {  // energies eW[w][kp] -> ewT[kp][w]
    int wb_ = tid & 15, kb_ = tid >> 4;
    int w0 = wb_ * 6, kp0 = kb_ * 6;
    f32x4 q0[6], q1[6], k0[6], k1[6];
    #pragma unroll
    for (int i = 0; i < 6; i++){
      q0[i] = *(const f32x4*)&qrL[(w0 + i) * 12];
      q1[i] = *(const f32x4*)&qrL[(w0 + i) * 12 + 4];
      k0[i] = *(const f32x4*)&krL[(kp0 + i) * 12];
      k1[i] = *(const f32x4*)&krL[(kp0 + i) * 12 + 4];
    }
    #pragma unroll
    for (int j = 0; j < 6; j++)
      #pragma unroll
      for (int i = 0; i < 6; i++){
        float e = 0.f;
        #pragma unroll
        for (int d = 0; d < 4; d++) e += q0[i][d] * k0[j][d] + q1[i][d] * k1[j][d];
        ewT[(kp0 + j) * 102 + (w0 + i)] = e;
      }
  }
  __syncthreads();
  #pragma unroll
  for (int t = 0; t < 24; t++){
    int w = wvid + t * 4;
    float x0 = pre0[t];
    float x1 = (lane < 32) ? pre1[t] : ewT[(lane - 32) * 102 + w];
    float x2 = ewT[(lane + 32) * 102 + w];
    float mx = fmaxf(x0, fmaxf(x1, x2));
    #pragma unroll
    for (int s = 32; s; s >>= 1) mx = fmaxf(mx, __shfl_xor(mx, s));
    float e0 = __expf(x0 - mx), e1 = __expf(x1 - mx), e2 = __expf(x2 - mx);
    float sm = e0 + e1 + e2;
    #pragma unroll
    for (int s = 32; s; s >>= 1) sm += __shfl_xor(sm, s);
    float inv = 1.f / sm;
    float* ebw = (float*)(ebase + (size_t)w * 96);
    ebw[lane] = e0 * inv;                                   // normalized eH -> global (f32, for colO)
    if (lane < 32) ebw[64 + lane] = e1 * inv;
    else           aW[(lane - 32) * 100 + w] = f2bf(e1 * inv);
    aW[(lane + 32) * 100 + w] = f2bf(e2 * inv);             // normalized eW -> LDS bf16
  }
  __syncthreads();
  float gm = gamma[0];
  int d0 = (tid & 15) * 4, w0 = (tid >> 4) * 6;
  f32x4 acc2[6];
  #pragma unroll
  for (int c = 0; c < 6; c++) acc2[c] = (f32x4)(0.f);
  for (int kp = 0; kp < 96; kp++){
    ushort4 vv4 = *(const ushort4*)&vL2[kp * 68 + d0];
    f32x4 vf; vf[0] = bf2f(vv4.x); vf[1] = bf2f(vv4.y); vf[2] = bf2f(vv4.z); vf[3] = bf2f(vv4.w);
    ushort2 a01 = *(const ushort2*)&aW[kp * 100 + w0];
    ushort2 a23 = *(const ushort2*)&aW[kp * 100 + w0 + 2];
    ushort2 a45 = *(const ushort2*)&aW[kp * 100 + w0 + 4];
    acc2[0] += vf * bf2f(a01.x); acc2[1] += vf * bf2f(a01.y);
    acc2[2] += vf * bf2f(a23.x); acc2[3] += vf * bf2f(a23.y);
    acc2[4] += vf * bf2f(a45.x); acc2[5] += vf * bf2f(a45.y);
  }
  #pragma unroll
  for (int c = 0; c < 6; c++){
    size_t pix = rowb + (w0 + c);
    ushort4 xr = *(const ushort4*)&xin[pix * 64 + d0];
    ushort4 ov;
    ov.x = f2bf(bf2f(xr.x) + gm * acc2[c][0]);
    ov.y = f2bf(bf2f(xr.y) + gm * acc2[c][1]);
    ov.z = f2bf(bf2f(xr.z) + gm * acc2[c][2]);
    ov.w = f2bf(bf2f(xr.w) + gm * acc2[c][3]);
    *(ushort4*)&xout[pix * 64 + d0] = ov;
  }
}

// ---------------- CCA: column kernel — oH + final accumulate (bf16 LDS operands) ----------------
__global__ __launch_bounds__(256, 2) void cca_colO_kernel(const float* __restrict__ vT,
    const float* __restrict__ gamma, const float* __restrict__ ebuf,
    const unsigned short* __restrict__ xpart, unsigned short* __restrict__ xout){
  int blk = blockIdx.x; int b = blk / 96, w = blk - b * 96;
  __shared__ unsigned short vL2[96 * 68];   // bf16 [kp(H)][d]
  __shared__ unsigned short aTb[96 * 100];  // bf16 [kp][hh]
  int tid = threadIdx.x;
  for (int i = tid; i < 6144; i += 256){
    int kp = i >> 6, d = i & 63;
    vL2[kp * 68 + d] = f2bf(vT[((size_t)(b * HW) + kp * 96 + w) * 64 + d]);
  }
  for (int i = tid; i < 9216; i += 256){
    int hh = i / 96, kp = i - hh * 96;
    aTb[kp * 100 + hh] = f2bf(ebuf[(((size_t)b * 96 + hh) * 96 + w) * 96 + kp]);
  }
  __syncthreads();
  float gm = gamma[0];
  int d0 = (tid & 15) * 4, h0 = (tid >> 4) * 6;
  f32x4 acc2[6];
  #pragma unroll
  for (int c = 0; c < 6; c++) acc2[c] = (f32x4)(0.f);
  for (int kp = 0; kp < 96; kp++){
    ushort4 vv4 = *(const ushort4*)&vL2[kp * 68 + d0];
    f32x4 vf; vf[0] = bf2f(vv4.x); vf[1] = bf2f(vv4.y); vf[2] = bf2f(vv4.z); vf[3] = bf2f(vv4.w);
    ushort2 a01 = *(const ushort2*)&aTb[kp * 100 + h0];
    ushort2 a23 = *(const ushort2*)&aTb[kp * 100 + h0 + 2];
    ushort2 a45 = *(const ushort2*)&aTb[kp * 100 + h0 + 4];
    acc2[0] += vf * bf2f(a01.x); acc2[1] += vf * bf2f(a01.y);
    acc2[2] += vf * bf2f(a23.x); acc2[3] += vf * bf2f(a23.y);
    acc2[4] += vf * bf2f(a45.x); acc2[5] += vf * bf2f(a45.y);
  }
  #pragma unroll
  for (int c = 0; c < 6; c++){
    size_t pix = (size_t)(b * HW) + (h0 + c) * 96 + w;
    ushort4 xr = *(const ushort4*)&xpart[pix * 64 + d0];
    ushort4 ov;
    ov.x = f2bf(bf2f(xr.x) + gm * acc2[c][0]);
    ov.y = f2bf(bf2f(xr.y) + gm * acc2[c][1]);
    ov.z = f2bf(bf2f(xr.z) + gm * acc2[c][2]);
    ov.w = f2bf(bf2f(xr.w) + gm * acc2[c][3]);
    *(ushort4*)&xout[pix * 64 + d0] = ov;
  }
}

// ---------------- bilinear x8 upsample (align_corners) of 19ch ----------------
__global__ void upsample_kernel(const float* __restrict__ t19, float* __restrict__ out){
  int gid = blockIdx.x * 256 + threadIdx.x;
  int xq = gid % 192; int t = gid / 192;
  int yy = t % 768; t /= 768;
  int o = t % 19; int b = t / 19;
  const float R = 95.0f / 767.0f;
  float ry = yy * R;
  int iy = (int)ry;
  float fy = ry - (float)iy;
  int iy1 = min(iy + 1, 95);
  const float* base = t19 + ((size_t)b * 19 + o) * HW;
  float4 res;
  float* rp = (float*)&res;
  #pragma unroll
  for (int j = 0; j < 4; j++){
    int xx = xq * 4 + j;
    float rx = xx * R;
    int ix = (int)rx; float fx = rx - (float)ix; int ix1 = min(ix + 1, 95);
    float v00 = base[iy * 96 + ix],  v01 = base[iy * 96 + ix1];
    float v10 = base[iy1 * 96 + ix], v11 = base[iy1 * 96 + ix1];
    rp[j] = (1.f - fy) * ((1.f - fx) * v00 + fx * v01) + fy * ((1.f - fx) * v10 + fx * v11);
  }
  *(float4*)(out + (((size_t)b * 19 + o) * 768 + yy) * 768 + xq * 4) = res;
}

// ---------------- host-side orchestration ----------------
extern "C" void kernel_launch(void* const* d_in, const int* in_sizes, int n_in,
                              void* d_out, int out_size, void* d_ws, size_t ws_size,
                              hipStream_t stream){
  const float* x       = (const float*)d_in[0];
  const float* w_in    = (const float*)d_in[1];
  const float* bn_in_g = (const float*)d_in[2];
  const float* bn_in_b = (const float*)d_in[3];
  const float* bn_in_m = (const float*)d_in[4];
  const float* bn_in_v = (const float*)d_in[5];
  const float* wq      = (const float*)d_in[6];
  const float* wk      = (const float*)d_in[7];
  const float* wv      = (const float*)d_in[8];
  const float* gamma   = (const float*)d_in[9];
  const float* w_out   = (const float*)d_in[10];
  const float* bn_o_g  = (const float*)d_in[11];
  const float* bn_o_b  = (const float*)d_in[12];
  const float* bn_o_m  = (const float*)d_in[13];
  const float* bn_o_v  = (const float*)d_in[14];
  const float* w_cls1  = (const float*)d_in[15];
  const float* bn_c_g  = (const float*)d_in[16];
  const float* bn_c_b  = (const float*)d_in[17];
  const float* bn_c_m  = (const float*)d_in[18];
  const float* bn_c_v  = (const float*)d_in[19];
  const float* w_cls2  = (const float*)d_in[20];
  float* out = (float*)d_out;

  char* ws = (char*)d_ws;
  size_t off = 0;
  auto alloc = [&](size_t bytes) -> void* {
    void* p = ws + off; off += (bytes + 255) & ~(size_t)255; return p;
  };
  const int KS = 12;
  const size_t NHWCb = (size_t)2 * HW * 64 * 2;                 // 2.36 MB
  unsigned short* xT   = (unsigned short*)alloc((size_t)2 * HW * 2048 * 2);       // 75.5 MB
  unsigned short* sl   = (unsigned short*)alloc((size_t)KS * 72 * 16384 * 2);     // 28.3 MB (also ebuf)
  float* ebuf = (float*)sl;                                     // CCA-phase reuse [b][h][w][96]
  unsigned short* xattA = (unsigned short*)alloc(NHWCb);
  unsigned short* xattB = (unsigned short*)alloc(NHWCb);
  unsigned short* Ptmp  = (unsigned short*)alloc(NHWCb);
  unsigned short* attT  = (unsigned short*)alloc(NHWCb);
  unsigned short* midT  = (unsigned short*)alloc(NHWCb);
  float* qb    = (float*)alloc((size_t)2 * HW * 8 * 4);
  float* kb    = (float*)alloc((size_t)2 * HW * 8 * 4);
  float* vb    = (float*)alloc((size_t)2 * HW * 64 * 4);
  float* t19   = (float*)alloc((size_t)2 * 19 * HW * 4);
  unsigned short* WpIn  = (unsigned short*)alloc((size_t)64 * 2048 * 9 * 2);
  unsigned short* WpOut = (unsigned short*)alloc((size_t)64 * 64 * 9 * 2);
  unsigned short* WpCls = (unsigned short*)alloc((size_t)64 * 2112 * 9 * 2);
  unsigned short* zp    = (unsigned short*)alloc(256);
  (void)ws_size; (void)in_sizes; (void)n_in; (void)out_size;

  hipMemsetAsync(zp, 0, 256, stream);
  transp_kernel<<<2304, 256, 0, stream>>>(x, xT);
  packw_kernel<<<1024, 256, 0, stream>>>(w_in,   WpIn,  2048);
  packw_kernel<<<64,   256, 0, stream>>>(w_out,  WpOut, 64);
  packw_kernel<<<1024, 256, 0, stream>>>(w_cls1, WpCls, 2112);

  // conv_in (2048 -> 64) + BN + ReLU -> xattA (NHWC bf16)
  conv_nhwc_kernel<<<dim3(72, KS), 256, 0, stream>>>(xT, 2048, nullptr, 64, WpIn, sl, 64, zp);
  bn_reduce_kernel<<<4608, 256, 0, stream>>>(sl, KS, bn_in_g, bn_in_b, bn_in_m, bn_in_v, 1, xattA);

  // CCA pass 1: xattA -> xattB
  cca_proj_kernel<<<144, 128, 0, stream>>>(xattA, wq, wk, wv, qb, kb, vb);
  cca_colE_kernel<<<192, 256, 0, stream>>>(qb, kb, ebuf);
  cca_rowSM_kernel<<<192, 256, 0, stream>>>(qb, kb, vb, xattA, gamma, ebuf, Ptmp);
  cca_colO_kernel<<<192, 256, 0, stream>>>(vb, gamma, ebuf, Ptmp, xattB);
  // CCA pass 2: xattB -> attT
  cca_proj_kernel<<<144, 128, 0, stream>>>(xattB, wq, wk, wv, qb, kb, vb);
  cca_colE_kernel<<<192, 256, 0, stream>>>(qb, kb, ebuf);
  cca_rowSM_kernel<<<192, 256, 0, stream>>>(qb, kb, vb, xattB, gamma, ebuf, Ptmp);
  cca_colO_kernel<<<192, 256, 0, stream>>>(vb, gamma, ebuf, Ptmp, attT);

  // conv_out (64 -> 64) + BN + ReLU -> midT
  conv_nhwc_kernel<<<dim3(72, 2), 256, 0, stream>>>(attT, 64, nullptr, 2, WpOut, sl, 2, zp);
  bn_reduce_kernel<<<4608, 256, 0, stream>>>(sl, 2, bn_o_g, bn_o_b, bn_o_m, bn_o_v, 1, midT);

  // cls1 conv on concat([x, mid]) (2112 -> 64) + BN + fused cls2 -> t19
  conv_nhwc_kernel<<<dim3(72, KS), 256, 0, stream>>>(xT, 2048, midT, 64, WpCls, sl, 66, zp);
  bn_reduce_cls_kernel<<<4608, 256, 0, stream>>>(sl, KS, bn_c_g, bn_c_b, bn_c_m, bn_c_v, w_cls2, t19);

  // bilinear x8 upsample of 19ch (commuted with 1x1 conv)
  upsample_kernel<<<21888, 256, 0, stream>>>(t19, out);
}